// Round 1
// baseline (896.230 us; speedup 1.0000x reference)
//
#include <hip/hip_runtime.h>
#include <hip/hip_bf16.h>

// Problem constants
#define F    1024
#define WW   512
#define DH   128          // head dim
#define NPAIR 64          // OC(8) * heads(8)

using short8  = __attribute__((ext_vector_type(8))) short;   // 8 bf16 (4 VGPRs)
using short4v = __attribute__((ext_vector_type(4))) short;   // 4 bf16 (8B)
using float4v = __attribute__((ext_vector_type(4))) float;   // MFMA C/D frag

__device__ __forceinline__ float bf2f(unsigned short u) {
    union { unsigned int i; float f; } x; x.i = ((unsigned int)u) << 16; return x.f;
}
__device__ __forceinline__ unsigned short f2bf(float f) {
    union { float f; unsigned int i; } x; x.f = f;
    unsigned int r = x.i + 0x7fff + ((x.i >> 16) & 1);   // RNE
    return (unsigned short)(r >> 16);
}

// ---------------------------------------------------------------------------
// LayerNorm over F axis per (c,w); virtual concat of up to 3 fp32 sources
// (8 channels each). out: bf16 (C, F, W). grid = C*32, block 256 (16w x 16f).
// ---------------------------------------------------------------------------
__global__ __launch_bounds__(256) void k_ln(
    const float* __restrict__ s0, const float* __restrict__ s1,
    const float* __restrict__ s2,
    const float* __restrict__ g, const float* __restrict__ b,
    unsigned short* __restrict__ out)
{
    int c  = blockIdx.x >> 5;
    int w0 = (blockIdx.x & 31) << 4;
    const float* src = (c < 8) ? s0 : (c < 16) ? s1 : s2;
    src += (size_t)(c & 7) * F * WW;
    int tx = threadIdx.x & 15, ty = threadIdx.x >> 4;

    float sum = 0.f, ssq = 0.f;
    for (int f = ty; f < F; f += 16) {
        float v = src[f * WW + w0 + tx];
        sum += v; ssq += v * v;
    }
    __shared__ float sm[16][17], sq[16][17];
    __shared__ float mu_s[16], rs_s[16];
    sm[ty][tx] = sum; sq[ty][tx] = ssq;
    __syncthreads();
    if (threadIdx.x < 16) {
        float s = 0.f, q = 0.f;
        #pragma unroll
        for (int i = 0; i < 16; i++) { s += sm[i][threadIdx.x]; q += sq[i][threadIdx.x]; }
        float mu  = s * (1.f / F);
        float var = q * (1.f / F) - mu * mu;     // biased var (jnp.var)
        mu_s[threadIdx.x] = mu;
        rs_s[threadIdx.x] = rsqrtf(var + 1e-8f);
    }
    __syncthreads();
    float mu = mu_s[tx], rs = rs_s[tx];
    unsigned short* o = out + (size_t)c * F * WW;
    for (int f = ty; f < F; f += 16) {
        float v = src[f * WW + w0 + tx];
        float r = (v - mu) * rs * g[c * F + f] + b[c * F + f];
        o[f * WW + w0 + tx] = f2bf(r);
    }
}

// ---------------------------------------------------------------------------
// 1x3 conv along W producing q,k,v (8 out-ch each). q,k stored TRANSPOSED
// [pair][w][j] (bf16); v stored natural [oc][f][w] (bf16) = PV A layout.
// Block swizzle: 16 consecutive virtual blocks (one 32-f group = one 64B line
// span of the transposed layout) land on the same XCD so partial lines merge
// in a single L2.
// ---------------------------------------------------------------------------
__global__ __launch_bounds__(256) void k_qkv(
    const unsigned short* __restrict__ srcQ, int CinQ, const float* __restrict__ wq,
    const void* __restrict__ srcKV, int kvBf16,
    const float* __restrict__ wk, const float* __restrict__ wv,
    unsigned short* __restrict__ qT, unsigned short* __restrict__ kT,
    unsigned short* __restrict__ v)
{
    // grid 512: vb = g*16 + i, phys = i*32 + g  (g = f-group of 32, i = sub)
    int vb = ((blockIdx.x & 31) << 4) + (blockIdx.x >> 5);
    int p0 = (vb * 256 + threadIdx.x) * 4;
    int f  = p0 >> 9;
    int w0 = p0 & 511;
    int h = f >> 7, jf = f & 127;

    // ---- Q ----
    float accq[8][4];
    #pragma unroll
    for (int o = 0; o < 8; o++) { accq[o][0]=0.f; accq[o][1]=0.f; accq[o][2]=0.f; accq[o][3]=0.f; }
    for (int ic = 0; ic < CinQ; ic++) {
        const unsigned short* s = srcQ + ((size_t)ic * F + f) * WW;
        float val[6];
        #pragma unroll
        for (int i = 0; i < 6; i++) {
            int w = w0 - 1 + i;
            val[i] = (w >= 0 && w < WW) ? bf2f(s[w]) : 0.f;
        }
        #pragma unroll
        for (int o = 0; o < 8; o++)
            #pragma unroll
            for (int t = 0; t < 3; t++) {
                float wt = wq[(o * CinQ + ic) * 3 + t];
                #pragma unroll
                for (int p = 0; p < 4; p++) accq[o][p] = fmaf(wt, val[p + t], accq[o][p]);
            }
    }
    #pragma unroll
    for (int o = 0; o < 8; o++)
        #pragma unroll
        for (int p = 0; p < 4; p++)
            qT[((size_t)(o * 8 + h) * WW + w0 + p) * DH + jf] = f2bf(accq[o][p]);

    // ---- K and V (8 in-ch always) ----
    float acck[8][4], accv[8][4];
    #pragma unroll
    for (int o = 0; o < 8; o++)
        #pragma unroll
        for (int p = 0; p < 4; p++) { acck[o][p] = 0.f; accv[o][p] = 0.f; }
    for (int ic = 0; ic < 8; ic++) {
        float val[6];
        if (kvBf16) {
            const unsigned short* s = (const unsigned short*)srcKV + ((size_t)ic * F + f) * WW;
            #pragma unroll
            for (int i = 0; i < 6; i++) {
                int w = w0 - 1 + i;
                val[i] = (w >= 0 && w < WW) ? bf2f(s[w]) : 0.f;
            }
        } else {
            const float* s = (const float*)srcKV + ((size_t)ic * F + f) * WW;
            #pragma unroll
            for (int i = 0; i < 6; i++) {
                int w = w0 - 1 + i;
                val[i] = (w >= 0 && w < WW) ? s[w] : 0.f;
            }
        }
        #pragma unroll
        for (int o = 0; o < 8; o++)
            #pragma unroll
            for (int t = 0; t < 3; t++) {
                float wtk = wk[(o * 8 + ic) * 3 + t];
                float wtv = wv[(o * 8 + ic) * 3 + t];
                #pragma unroll
                for (int p = 0; p < 4; p++) {
                    acck[o][p] = fmaf(wtk, val[p + t], acck[o][p]);
                    accv[o][p] = fmaf(wtv, val[p + t], accv[o][p]);
                }
            }
    }
    #pragma unroll
    for (int o = 0; o < 8; o++) {
        #pragma unroll
        for (int p = 0; p < 4; p++)
            kT[((size_t)(o * 8 + h) * WW + w0 + p) * DH + jf] = f2bf(acck[o][p]);
        short4v pv;
        #pragma unroll
        for (int p = 0; p < 4; p++) pv[p] = (short)f2bf(accv[o][p]);
        *(short4v*)(v + ((size_t)o * F + f) * WW + w0) = pv;
    }
}

// ---------------------------------------------------------------------------
// Fused flash attention: S^T = K.Q^T via MFMA (D[k][q]), + up to 3 fp32
// biases, write pq, online softmax (m/l/alpha in registers), P via
// wave-private LDS rows to PV B layout, PV via MFMA.
// Changes vs prev: (1) Q fragments load direct global->reg (no Qs LDS,
// 62->45KB); (2) bias loads hoisted to chunk top, overlapping K/V staging
// (issue-early/consume-late; they drain at the same barrier the staging
// needs anyway); (3) pair-major block swizzle: the 8 q-tiles of a pair are
// phys ids == pair (mod 8) -> same XCD -> K/V re-reads hit one L2.
// Block: 256 thr (4 waves x 16 q rows). grid = 512.
// ---------------------------------------------------------------------------
__global__ __launch_bounds__(256) void k_attn(
    const unsigned short* __restrict__ qT, const unsigned short* __restrict__ kT,
    const unsigned short* __restrict__ v,
    const float* __restrict__ a0, const float* __restrict__ a1,
    const float* __restrict__ a2, int nsrc,
    float* __restrict__ pq, unsigned short* __restrict__ aout)
{
    int pair = blockIdx.x & 63;          // phys mod 8 == pair mod 8 -> same XCD
    int qw0  = (blockIdx.x >> 6) << 6;

    __shared__ unsigned short Ks[64 * 136];   // [k][d], pad 8 -> row 272B
    __shared__ unsigned short Vt[128 * 72];   // [d][k-chunk], pad 8 -> row 144B
    __shared__ unsigned short P [64 * 72];    // [q][k-chunk], wave-private rows

    int tid = threadIdx.x;
    const unsigned short* qb = qT + ((size_t)pair * WW + qw0) * DH;
    const unsigned short* kb = kT + (size_t)pair * WW * DH;
    const unsigned short* vb = v  + (size_t)pair * DH * WW;

    int wv = tid >> 6, lane = tid & 63;
    int lr = lane & 15, lkg = lane >> 4;
    int qrow = qw0 + wv * 16 + lr;

    // Q fragments: straight global -> registers (read once per block)
    short8 bq[4];
    #pragma unroll
    for (int dk = 0; dk < 4; dk++)
        bq[dk] = *(const short8*)(qb + (size_t)(wv * 16 + lr) * DH + dk * 32 + lkg * 8);

    float4v acc[8] = {};
    float mrun = -1e30f, lrun = 0.f;
    const float scale = 0.08838834764831845f;   // 1/sqrt(128)
    size_t bbase = (size_t)pair * WW * WW + (size_t)qrow * WW;

    for (int kc = 0; kc < 8; kc++) {
        __syncthreads();   // prior chunk's Ks/Vt/P reads done

        // ---- bias loads issued EARLY: overlap the K/V staging below and
        // drain at the same barrier the staging requires anyway.
        float4v b0v[4], b1v[4], b2v[4];
        #pragma unroll
        for (int mi = 0; mi < 4; mi++)
            b0v[mi] = *(const float4v*)(a0 + bbase + kc * 64 + mi * 16 + lkg * 4);
        if (nsrc > 1) {
            #pragma unroll
            for (int mi = 0; mi < 4; mi++)
                b1v[mi] = *(const float4v*)(a1 + bbase + kc * 64 + mi * 16 + lkg * 4);
        }
        if (nsrc > 2) {
            #pragma unroll
            for (int mi = 0; mi < 4; mi++)
                b2v[mi] = *(const float4v*)(a2 + bbase + kc * 64 + mi * 16 + lkg * 4);
        }

        #pragma unroll
        for (int it = 0; it < 4; it++) {      // K chunk 64x128
            int idx = it * 256 + tid;
            int r = idx >> 4, c = idx & 15;
            *(short8*)(Ks + r * 136 + c * 8) =
                *(const short8*)(kb + (size_t)(kc * 64 + r) * DH + c * 8);
        }
        #pragma unroll
        for (int it = 0; it < 4; it++) {      // V chunk 128x64
            int idx = it * 256 + tid;
            int j = idx >> 3, c = idx & 7;
            *(short8*)(Vt + j * 72 + c * 8) =
                *(const short8*)(vb + (size_t)j * WW + kc * 64 + c * 8);
        }
        __syncthreads();

        // S^T: D[k 64][q 16-per-wave], contraction over d=128
        float4v sacc[4] = {};
        #pragma unroll
        for (int dk = 0; dk < 4; dk++) {
            short8 ak[4];
            #pragma unroll
            for (int mi = 0; mi < 4; mi++)
                ak[mi] = *(const short8*)(Ks + (mi * 16 + lr) * 136 + dk * 32 + lkg * 8);
            #pragma unroll
            for (int mi = 0; mi < 4; mi++)
                sacc[mi] = __builtin_amdgcn_mfma_f32_16x16x32_bf16(ak[mi], bq[dk], sacc[mi], 0, 0, 0);
        }

        // bias combine (regs already in flight), pq write, running max
        float sv[4][4];
        float mx = -1e30f;
        #pragma unroll
        for (int mi = 0; mi < 4; mi++) {
            int k0 = kc * 64 + mi * 16 + lkg * 4;
            float4v s;
            #pragma unroll
            for (int r = 0; r < 4; r++) s[r] = sacc[mi][r] * scale + b0v[mi][r];
            if (nsrc > 1) {
                #pragma unroll
                for (int r = 0; r < 4; r++) s[r] += b1v[mi][r];
            }
            if (nsrc > 2) {
                #pragma unroll
                for (int r = 0; r < 4; r++) s[r] += b2v[mi][r];
            }
            *(float4v*)(pq + bbase + k0) = s;
            #pragma unroll
            for (int r = 0; r < 4; r++) { sv[mi][r] = s[r]; mx = fmaxf(mx, s[r]); }
        }
        mx = fmaxf(mx, __shfl_xor(mx, 16));
        mx = fmaxf(mx, __shfl_xor(mx, 32));
        float mnew  = fmaxf(mrun, mx);
        float alpha = __expf(mrun - mnew);
        float lsum  = 0.f;
        #pragma unroll
        for (int mi = 0; mi < 4; mi++) {
            short4v pk;
            #pragma unroll
            for (int r = 0; r < 4; r++) {
                float e = __expf(sv[mi][r] - mnew);
                lsum += e;
                pk[r] = (short)f2bf(e);
            }
            *(short4v*)(P + (wv * 16 + lr) * 72 + mi * 16 + lkg * 4) = pk;
        }
        lsum += __shfl_xor(lsum, 16);
        lsum += __shfl_xor(lsum, 32);
        lrun = lrun * alpha + lsum;
        mrun = mnew;

        #pragma unroll
        for (int mt = 0; mt < 8; mt++)
            #pragma unroll
            for (int r = 0; r < 4; r++) acc[mt][r] *= alpha;

        // PV: D[d 128][q 16], contraction over this 64-k chunk
        #pragma unroll
        for (int ks = 0; ks < 2; ks++) {
            short8 bp = *(const short8*)(P + (wv * 16 + lr) * 72 + ks * 32 + lkg * 8);
            #pragma unroll
            for (int mt = 0; mt < 8; mt++) {
                short8 av = *(const short8*)(Vt + (mt * 16 + lr) * 72 + ks * 32 + lkg * 8);
                acc[mt] = __builtin_amdgcn_mfma_f32_16x16x32_bf16(av, bp, acc[mt], 0, 0, 0);
            }
        }
    }

    float linv = 1.f / lrun;
    unsigned short* ab = aout + (size_t)pair * DH * WW + qw0 + wv * 16 + lr;
    #pragma unroll
    for (int mt = 0; mt < 8; mt++)
        #pragma unroll
        for (int r = 0; r < 4; r++) {
            int d = mt * 16 + lkg * 4 + r;
            ab[(size_t)d * WW] = f2bf(acc[mt][r] * linv);
        }
}

// ---------------------------------------------------------------------------
// wo conv: 1x3, 8->8, bf16 in (natural), fp32 out. 4 points/thread.
// ---------------------------------------------------------------------------
__global__ __launch_bounds__(256) void k_wo(
    const unsigned short* __restrict__ a, const float* __restrict__ w,
    float* __restrict__ z)
{
    int p0 = (blockIdx.x * 256 + threadIdx.x) * 4;
    int f = p0 >> 9, w0 = p0 & 511;
    float acc[8][4];
    #pragma unroll
    for (int o = 0; o < 8; o++)
        #pragma unroll
        for (int p = 0; p < 4; p++) acc[o][p] = 0.f;
    for (int ic = 0; ic < 8; ic++) {
        const unsigned short* s = a + ((size_t)ic * F + f) * WW;
        float val[6];
        #pragma unroll
        for (int i = 0; i < 6; i++) {
            int ww = w0 - 1 + i;
            val[i] = (ww >= 0 && ww < WW) ? bf2f(s[ww]) : 0.f;
        }
        #pragma unroll
        for (int o = 0; o < 8; o++)
            #pragma unroll
            for (int t = 0; t < 3; t++) {
                float wt = w[(o * 8 + ic) * 3 + t];
                #pragma unroll
                for (int p = 0; p < 4; p++) acc[o][p] = fmaf(wt, val[p + t], acc[o][p]);
            }
    }
    #pragma unroll
    for (int o = 0; o < 8; o++) {
        float4v ov;
        #pragma unroll
        for (int p = 0; p < 4; p++) ov[p] = acc[o][p];
        *(float4v*)(z + ((size_t)o * F + f) * WW + w0) = ov;
    }
}

// ---------------------------------------------------------------------------
// Weight transpose prep: wc1 (32,24,3,3)->[tap][32], wc2 (8,32,3,3)->[tap][8]
// ---------------------------------------------------------------------------
__global__ void k_prep(const float* __restrict__ wc1, const float* __restrict__ wc2,
                       float* __restrict__ wT1, float* __restrict__ wT2)
{
    int i = blockIdx.x * 256 + threadIdx.x;
    if (i < 6912) { int oc = i / 216, rem = i % 216; wT1[rem * 32 + oc] = wc1[i]; }
    if (i < 2304) { int oc = i / 288, rem = i % 288; wT2[rem * 8 + oc] = wc2[i]; }
}

// ---------------------------------------------------------------------------
// 3x3 conv, 24->32, + SquaredReLU. bf16 in/out.
// ---------------------------------------------------------------------------
__global__ __launch_bounds__(256) void k_conv1(
    const unsigned short* __restrict__ x, const float* __restrict__ wT,
    unsigned short* __restrict__ t)
{
    int p = blockIdx.x * 256 + threadIdx.x;
    int f = p >> 9, w0 = p & 511;
    float acc[32];
    #pragma unroll
    for (int o = 0; o < 32; o++) acc[o] = 0.f;
    for (int ic = 0; ic < 24; ic++) {
        const unsigned short* s = x + (size_t)ic * F * WW;
        #pragma unroll
        for (int dy = 0; dy < 3; dy++) {
            int ff = f + dy - 1;
            if (ff < 0 || ff >= F) continue;
            float vv[3];
            vv[0] = (w0 > 0)      ? bf2f(s[(size_t)ff * WW + w0 - 1]) : 0.f;
            vv[1] =                 bf2f(s[(size_t)ff * WW + w0]);
            vv[2] = (w0 < WW - 1) ? bf2f(s[(size_t)ff * WW + w0 + 1]) : 0.f;
            #pragma unroll
            for (int dx = 0; dx < 3; dx++) {
                const float* wt = wT + ((ic * 3 + dy) * 3 + dx) * 32;
                float val = vv[dx];
                #pragma unroll
                for (int o = 0; o < 32; o++) acc[o] = fmaf(wt[o], val, acc[o]);
            }
        }
    }
    #pragma unroll
    for (int o = 0; o < 32; o++) {
        float r = fmaxf(acc[o], 0.f);
        t[((size_t)o * F + f) * WW + w0] = f2bf(r * r);
    }
}

// ---------------------------------------------------------------------------
// 3x3 conv, 32->8, + residual x. bf16 in, fp32 out (final output 0).
// ---------------------------------------------------------------------------
__global__ __launch_bounds__(256) void k_conv2(
    const unsigned short* __restrict__ t, const float* __restrict__ wT,
    const float* __restrict__ x, float* __restrict__ out)
{
    int p = blockIdx.x * 256 + threadIdx.x;
    int f = p >> 9, w0 = p & 511;
    float acc[8];
    #pragma unroll
    for (int o = 0; o < 8; o++) acc[o] = 0.f;
    for (int ic = 0; ic < 32; ic++) {
        const unsigned short* s = t + (size_t)ic * F * WW;
        #pragma unroll
        for (int dy = 0; dy < 3; dy++) {
            int ff = f + dy - 1;
            if (ff < 0 || ff >= F) continue;
            float vv[3];
            vv[0] = (w0 > 0)      ? bf2f(s[(size_t)ff * WW + w0 - 1]) : 0.f;
            vv[1] =                 bf2f(s[(size_t)ff * WW + w0]);
            vv[2] = (w0 < WW - 1) ? bf2f(s[(size_t)ff * WW + w0 + 1]) : 0.f;
            #pragma unroll
            for (int dx = 0; dx < 3; dx++) {
                const float* wt = wT + ((ic * 3 + dy) * 3 + dx) * 8;
                float val = vv[dx];
                #pragma unroll
                for (int o = 0; o < 8; o++) acc[o] = fmaf(wt[o], val, acc[o]);
            }
        }
    }
    #pragma unroll
    for (int o = 0; o < 8; o++)
        out[((size_t)o * F + f) * WW + w0] = x[((size_t)o * F + f) * WW + w0] + acc[o];
}

// ---------------------------------------------------------------------------
extern "C" void kernel_launch(void* const* d_in, const int* in_sizes, int n_in,
                              void* d_out, int out_size, void* d_ws, size_t ws_size,
                              hipStream_t stream) {
    const float* x        = (const float*)d_in[0];
    const float* skip     = (const float*)d_in[1];
    const float* prev_qk1 = (const float*)d_in[2];
    const float* prev_qk2 = (const float*)d_in[3];
    const float* skip_qk  = (const float*)d_in[4];
    const float* g1  = (const float*)d_in[5];
    const float* b1  = (const float*)d_in[6];
    const float* wq1 = (const float*)d_in[7];
    const float* wk1 = (const float*)d_in[8];
    const float* wv1 = (const float*)d_in[9];
    const float* wo1 = (const float*)d_in[10];
    const float* g2  = (const float*)d_in[11];
    const float* b2  = (const float*)d_in[12];
    const float* wq2 = (const float*)d_in[13];
    const float* wk2 = (const float*)d_in[14];
    const float* wv2 = (const float*)d_in[15];
    const float* wo2 = (const float*)d_in[16];
    const float* g3  = (const float*)d_in[17];
    const float* b3  = (const float*)d_in[18];
    const float* wc1 = (const float*)d_in[19];
    const float* wc2 = (const float*)d_in[20];

    char* ws = (char*)d_ws;
    unsigned short* qT = (unsigned short*)(ws + 0);          //  8.39MB bf16 [pair][w][j]
    unsigned short* kT = (unsigned short*)(ws + 8388608);    //  8.39MB
    unsigned short* vB = (unsigned short*)(ws + 16777216);   //  8.39MB natural
    unsigned short* nh = (unsigned short*)(ws + 25165824);   // 25.17MB ln out, reused
    unsigned short* aB = (unsigned short*)(ws + 50331648);   //  8.39MB attn out
    float*          z1 = (float*)(ws + 58720256);            // 16.78MB
    float*          z2 = (float*)(ws + 75497472);            // 16.78MB
    unsigned short* tB = (unsigned short*)(ws + 92274688);   // 33.55MB sqrelu intermediate
    float*         wT1 = (float*)(ws + 125829120);
    float*         wT2 = (float*)(ws + 125856768);

    float* out0 = (float*)d_out;
    float* pq1  = out0 + 4194304;
    float* pq2  = pq1 + 16777216;

    k_prep<<<27, 256, 0, stream>>>(wc1, wc2, wT1, wT2);

    // --- attn1: x -> ln1 -> qkv -> fused(QK^T + prev_qk1+skip_qk -> pq1, softmax.V) -> wo
    k_ln  <<<8 * 32,  256, 0, stream>>>(x, nullptr, nullptr, g1, b1, nh);
    k_qkv <<<512,     256, 0, stream>>>(nh, 8, wq1, nh, 1, wk1, wv1, qT, kT, vB);
    k_attn<<<512,     256, 0, stream>>>(qT, kT, vB, prev_qk1, skip_qk, nullptr, 2, pq1, aB);
    k_wo  <<<512,     256, 0, stream>>>(aB, wo1, z1);

    // --- attn2: [x,z1] -> ln2 -> q ; k,v from raw skip ; pq2 = qk2 + skip_qk+pq1+prev_qk2
    k_ln  <<<16 * 32, 256, 0, stream>>>(x, z1, nullptr, g2, b2, nh);
    k_qkv <<<512,     256, 0, stream>>>(nh, 16, wq2, skip, 0, wk2, wv2, qT, kT, vB);
    k_attn<<<512,     256, 0, stream>>>(qT, kT, vB, skip_qk, pq1, prev_qk2, 3, pq2, aB);
    k_wo  <<<512,     256, 0, stream>>>(aB, wo2, z2);

    // --- MLP: ln3([x,z1,z2]) -> conv3x3(24->32) -> sqrelu -> conv3x3(32->8) + x
    k_ln   <<<24 * 32, 256, 0, stream>>>(x, z1, z2, g3, b3, nh);
    k_conv1<<<2048,    256, 0, stream>>>(nh, wT1, tB);
    k_conv2<<<2048,    256, 0, stream>>>(tB, wT2, x, out0);
}

// Round 2
// 771.129 us; speedup vs baseline: 1.1622x; 1.1622x over previous
//
#include <hip/hip_runtime.h>
#include <hip/hip_bf16.h>

// Problem constants
#define F    1024
#define WW   512
#define DH   128          // head dim
#define NPAIR 64          // OC(8) * heads(8)
#define PW   514          // padded width  (512 + 2)
#define PF   1026         // padded height (1024 + 2)

using short8  = __attribute__((ext_vector_type(8))) short;   // 8 bf16 (4 VGPRs)
using short4v = __attribute__((ext_vector_type(4))) short;   // 4 bf16 (8B)
using float4v = __attribute__((ext_vector_type(4))) float;   // MFMA C/D frag

__device__ __forceinline__ float bf2f(unsigned short u) {
    union { unsigned int i; float f; } x; x.i = ((unsigned int)u) << 16; return x.f;
}
__device__ __forceinline__ unsigned short f2bf(float f) {
    union { float f; unsigned int i; } x; x.f = f;
    unsigned int r = x.i + 0x7fff + ((x.i >> 16) & 1);   // RNE
    return (unsigned short)(r >> 16);
}

// ---------------------------------------------------------------------------
// LayerNorm over F axis per (c,w); virtual concat of up to 2 fp32 sources
// (8 channels each). out: bf16 (C, F, W) channel-first (attn path).
// grid = C*32, block 256 (16w x 16f).
// ---------------------------------------------------------------------------
__global__ __launch_bounds__(256) void k_ln(
    const float* __restrict__ s0, const float* __restrict__ s1,
    const float* __restrict__ s2,
    const float* __restrict__ g, const float* __restrict__ b,
    unsigned short* __restrict__ out)
{
    int c  = blockIdx.x >> 5;
    int w0 = (blockIdx.x & 31) << 4;
    const float* src = (c < 8) ? s0 : (c < 16) ? s1 : s2;
    src += (size_t)(c & 7) * F * WW;
    int tx = threadIdx.x & 15, ty = threadIdx.x >> 4;

    float sum = 0.f, ssq = 0.f;
    for (int f = ty; f < F; f += 16) {
        float v = src[f * WW + w0 + tx];
        sum += v; ssq += v * v;
    }
    __shared__ float sm[16][17], sq[16][17];
    __shared__ float mu_s[16], rs_s[16];
    sm[ty][tx] = sum; sq[ty][tx] = ssq;
    __syncthreads();
    if (threadIdx.x < 16) {
        float s = 0.f, q = 0.f;
        #pragma unroll
        for (int i = 0; i < 16; i++) { s += sm[i][threadIdx.x]; q += sq[i][threadIdx.x]; }
        float mu  = s * (1.f / F);
        float var = q * (1.f / F) - mu * mu;     // biased var (jnp.var)
        mu_s[threadIdx.x] = mu;
        rs_s[threadIdx.x] = rsqrtf(var + 1e-8f);
    }
    __syncthreads();
    float mu = mu_s[tx], rs = rs_s[tx];
    unsigned short* o = out + (size_t)c * F * WW;
    for (int f = ty; f < F; f += 16) {
        float v = src[f * WW + w0 + tx];
        float r = (v - mu) * rs * g[c * F + f] + b[c * F + f];
        o[f * WW + w0 + tx] = f2bf(r);
    }
}

// ---------------------------------------------------------------------------
// LN3 stats: mu/rsigma per (c,w) over F, 24 channels from x,z1,z2.
// grid = 24*32, block 256 (16w x 16f).
// ---------------------------------------------------------------------------
__global__ __launch_bounds__(256) void k_ln3_stats(
    const float* __restrict__ s0, const float* __restrict__ s1,
    const float* __restrict__ s2,
    float* __restrict__ mu3, float* __restrict__ rs3)
{
    int c  = blockIdx.x >> 5;
    int w0 = (blockIdx.x & 31) << 4;
    const float* src = (c < 8) ? s0 : (c < 16) ? s1 : s2;
    src += (size_t)(c & 7) * F * WW;
    int tx = threadIdx.x & 15, ty = threadIdx.x >> 4;

    float sum = 0.f, ssq = 0.f;
    for (int f = ty; f < F; f += 16) {
        float v = src[f * WW + w0 + tx];
        sum += v; ssq += v * v;
    }
    __shared__ float sm[16][17], sq[16][17];
    sm[ty][tx] = sum; sq[ty][tx] = ssq;
    __syncthreads();
    if (threadIdx.x < 16) {
        float s = 0.f, q = 0.f;
        #pragma unroll
        for (int i = 0; i < 16; i++) { s += sm[i][threadIdx.x]; q += sq[i][threadIdx.x]; }
        float mu  = s * (1.f / F);
        float var = q * (1.f / F) - mu * mu;
        mu3[c * WW + w0 + threadIdx.x] = mu;
        rs3[c * WW + w0 + threadIdx.x] = rsqrtf(var + 1e-8f);
    }
}

// ---------------------------------------------------------------------------
// LN3 apply: write nh3p channel-last padded [PF][PW][32] bf16; interior only.
// channels 24..31 = 0. One point per thread, 64B coalesced store.
// grid = 2048, block 256.
// ---------------------------------------------------------------------------
__global__ __launch_bounds__(256) void k_ln3_apply(
    const float* __restrict__ s0, const float* __restrict__ s1,
    const float* __restrict__ s2,
    const float* __restrict__ mu3, const float* __restrict__ rs3,
    const float* __restrict__ g, const float* __restrict__ b,
    unsigned short* __restrict__ outp)
{
    int p = blockIdx.x * 256 + threadIdx.x;
    int f = p >> 9, w = p & 511;
    unsigned short buf[32];
    #pragma unroll
    for (int c = 0; c < 24; c++) {
        const float* src = (c < 8) ? s0 : (c < 16) ? s1 : s2;
        float v = src[((size_t)(c & 7) * F + f) * WW + w];
        float r = (v - mu3[c * WW + w]) * rs3[c * WW + w] * g[c * F + f] + b[c * F + f];
        buf[c] = f2bf(r);
    }
    #pragma unroll
    for (int c = 24; c < 32; c++) buf[c] = 0;
    unsigned short* op = outp + ((size_t)(f + 1) * PW + (w + 1)) * 32;
    #pragma unroll
    for (int q = 0; q < 4; q++) *(short8*)(op + q * 8) = *(const short8*)(buf + q * 8);
}

// ---------------------------------------------------------------------------
// Zero the spatial pad cells of the two padded channel-last buffers.
// 3076 pad points x 64B each. grid 13, block 256.
// ---------------------------------------------------------------------------
__global__ void k_pad(unsigned short* __restrict__ a, unsigned short* __restrict__ b)
{
    int i = blockIdx.x * 256 + threadIdx.x;
    if (i >= 3076) return;
    int f, w;
    if (i < 514)       { f = 0;    w = i; }
    else if (i < 1028) { f = 1025; w = i - 514; }
    else { int j = i - 1028; f = 1 + (j >> 1); w = (j & 1) ? 513 : 0; }
    size_t off = ((size_t)f * PW + w) * 32;
    short8 z = {};
    #pragma unroll
    for (int q = 0; q < 4; q++) {
        *(short8*)(a + off + q * 8) = z;
        *(short8*)(b + off + q * 8) = z;
    }
}

// ---------------------------------------------------------------------------
// Weight prep: pack conv weights as bf16 MFMA A-fragments.
// A1: [ (tap*2+m)*16 + o ][ 32ic ]  (ic 24..31 zero)   9216 elems
// A2: [ tap*16 + o ][ 32ic ]        (o 8..15 zero)     4608 elems
// ---------------------------------------------------------------------------
__global__ void k_prep(const float* __restrict__ wc1, const float* __restrict__ wc2,
                       unsigned short* __restrict__ A1, unsigned short* __restrict__ A2)
{
    int i = blockIdx.x * 256 + threadIdx.x;
    if (i < 9216) {
        int ic = i & 31, row = i >> 5;       // row 0..287
        int o16 = row & 15, tm = row >> 4;   // tm 0..17
        int tap = tm >> 1, m = tm & 1;
        int oc = m * 16 + o16;
        A1[i] = (ic < 24) ? f2bf(wc1[(oc * 24 + ic) * 9 + tap]) : (unsigned short)0;
    }
    if (i < 4608) {
        int ic = i & 31, row = i >> 5;       // 0..143
        int o = row & 15, tap = row >> 4;
        A2[i] = (o < 8) ? f2bf(wc2[(o * 32 + ic) * 9 + tap]) : (unsigned short)0;
    }
}

// ---------------------------------------------------------------------------
// conv1 via implicit-GEMM MFMA: 24(->32 pad)ch -> 32ch, 3x3, + SquaredReLU.
// In/out channel-last padded [PF][PW][32] bf16. B-frags read straight from
// global (16B/lane, line-coalesced); A preloaded to regs (18 frags).
// Tile: 16 w-points (n) x 32 oc (2 m-frags), 9 taps = K-chunks.
// grid 2048 (f*2+half), 4 waves x 4 iters = 32 w-tiles per f row.
// ---------------------------------------------------------------------------
__global__ __launch_bounds__(256) void k_conv1m(
    const unsigned short* __restrict__ inp, const unsigned short* __restrict__ A1,
    unsigned short* __restrict__ outp)
{
    int wv = threadIdx.x >> 6, lane = threadIdx.x & 63;
    int lr = lane & 15, lkg = lane >> 4;

    short8 a[9][2];
    #pragma unroll
    for (int tap = 0; tap < 9; tap++)
        #pragma unroll
        for (int m = 0; m < 2; m++)
            a[tap][m] = *(const short8*)(A1 + ((tap * 2 + m) * 16 + lr) * 32 + lkg * 8);

    int f = blockIdx.x >> 1;
    int half = blockIdx.x & 1;
    for (int it = 0; it < 4; it++) {
        int w0 = (half * 16 + wv * 4 + it) * 16;
        float4v acc0 = {}, acc1 = {};
        #pragma unroll
        for (int dy = 0; dy < 3; dy++)
            #pragma unroll
            for (int dx = 0; dx < 3; dx++) {
                short8 bfrag = *(const short8*)(inp +
                    ((size_t)(f + dy) * PW + (w0 + lr + dx)) * 32 + lkg * 8);
                acc0 = __builtin_amdgcn_mfma_f32_16x16x32_bf16(a[dy*3+dx][0], bfrag, acc0, 0, 0, 0);
                acc1 = __builtin_amdgcn_mfma_f32_16x16x32_bf16(a[dy*3+dx][1], bfrag, acc1, 0, 0, 0);
            }
        unsigned short* op = outp + ((size_t)(f + 1) * PW + (w0 + lr + 1)) * 32;
        short4v o0, o1;
        #pragma unroll
        for (int r = 0; r < 4; r++) {
            float v0 = fmaxf(acc0[r], 0.f);
            float v1 = fmaxf(acc1[r], 0.f);
            o0[r] = (short)f2bf(v0 * v0);
            o1[r] = (short)f2bf(v1 * v1);
        }
        *(short4v*)(op + lkg * 4)      = o0;   // oc 0..15
        *(short4v*)(op + 16 + lkg * 4) = o1;   // oc 16..31
    }
}

// ---------------------------------------------------------------------------
// conv2 via implicit-GEMM MFMA: 32ch -> 8ch (pad 16), 3x3, + residual x.
// In channel-last padded bf16; out channel-first fp32 (final output layout).
// ---------------------------------------------------------------------------
__global__ __launch_bounds__(256) void k_conv2m(
    const unsigned short* __restrict__ inp, const unsigned short* __restrict__ A2,
    const float* __restrict__ x, float* __restrict__ out)
{
    int wv = threadIdx.x >> 6, lane = threadIdx.x & 63;
    int lr = lane & 15, lkg = lane >> 4;

    short8 a[9];
    #pragma unroll
    for (int tap = 0; tap < 9; tap++)
        a[tap] = *(const short8*)(A2 + (tap * 16 + lr) * 32 + lkg * 8);

    int f = blockIdx.x >> 1;
    int half = blockIdx.x & 1;
    for (int it = 0; it < 4; it++) {
        int w0 = (half * 16 + wv * 4 + it) * 16;
        float4v acc = {};
        #pragma unroll
        for (int dy = 0; dy < 3; dy++)
            #pragma unroll
            for (int dx = 0; dx < 3; dx++) {
                short8 bfrag = *(const short8*)(inp +
                    ((size_t)(f + dy) * PW + (w0 + lr + dx)) * 32 + lkg * 8);
                acc = __builtin_amdgcn_mfma_f32_16x16x32_bf16(a[dy*3+dx], bfrag, acc, 0, 0, 0);
            }
        if (lkg < 2) {
            #pragma unroll
            for (int r = 0; r < 4; r++) {
                int oc = lkg * 4 + r;
                size_t off = ((size_t)oc * F + f) * WW + w0 + lr;
                out[off] = x[off] + acc[r];
            }
        }
    }
}

// ---------------------------------------------------------------------------
// 1x3 conv along W producing q,k,v (8 out-ch each). q,k stored TRANSPOSED
// [pair][w][j] (bf16); v stored natural [oc][f][w] (bf16) = PV A layout.
// ---------------------------------------------------------------------------
__global__ __launch_bounds__(256) void k_qkv(
    const unsigned short* __restrict__ srcQ, int CinQ, const float* __restrict__ wq,
    const void* __restrict__ srcKV, int kvBf16,
    const float* __restrict__ wk, const float* __restrict__ wv,
    unsigned short* __restrict__ qT, unsigned short* __restrict__ kT,
    unsigned short* __restrict__ v)
{
    // grid 512: vb = g*16 + i, phys = i*32 + g  (g = f-group of 32, i = sub)
    int vb = ((blockIdx.x & 31) << 4) + (blockIdx.x >> 5);
    int p0 = (vb * 256 + threadIdx.x) * 4;
    int f  = p0 >> 9;
    int w0 = p0 & 511;
    int h = f >> 7, jf = f & 127;

    // ---- Q ----
    float accq[8][4];
    #pragma unroll
    for (int o = 0; o < 8; o++) { accq[o][0]=0.f; accq[o][1]=0.f; accq[o][2]=0.f; accq[o][3]=0.f; }
    for (int ic = 0; ic < CinQ; ic++) {
        const unsigned short* s = srcQ + ((size_t)ic * F + f) * WW;
        float val[6];
        #pragma unroll
        for (int i = 0; i < 6; i++) {
            int w = w0 - 1 + i;
            val[i] = (w >= 0 && w < WW) ? bf2f(s[w]) : 0.f;
        }
        #pragma unroll
        for (int o = 0; o < 8; o++)
            #pragma unroll
            for (int t = 0; t < 3; t++) {
                float wt = wq[(o * CinQ + ic) * 3 + t];
                #pragma unroll
                for (int p = 0; p < 4; p++) accq[o][p] = fmaf(wt, val[p + t], accq[o][p]);
            }
    }
    #pragma unroll
    for (int o = 0; o < 8; o++)
        #pragma unroll
        for (int p = 0; p < 4; p++)
            qT[((size_t)(o * 8 + h) * WW + w0 + p) * DH + jf] = f2bf(accq[o][p]);

    // ---- K and V (8 in-ch always) ----
    float acck[8][4], accv[8][4];
    #pragma unroll
    for (int o = 0; o < 8; o++)
        #pragma unroll
        for (int p = 0; p < 4; p++) { acck[o][p] = 0.f; accv[o][p] = 0.f; }
    for (int ic = 0; ic < 8; ic++) {
        float val[6];
        if (kvBf16) {
            const unsigned short* s = (const unsigned short*)srcKV + ((size_t)ic * F + f) * WW;
            #pragma unroll
            for (int i = 0; i < 6; i++) {
                int w = w0 - 1 + i;
                val[i] = (w >= 0 && w < WW) ? bf2f(s[w]) : 0.f;
            }
        } else {
            const float* s = (const float*)srcKV + ((size_t)ic * F + f) * WW;
            #pragma unroll
            for (int i = 0; i < 6; i++) {
                int w = w0 - 1 + i;
                val[i] = (w >= 0 && w < WW) ? s[w] : 0.f;
            }
        }
        #pragma unroll
        for (int o = 0; o < 8; o++)
            #pragma unroll
            for (int t = 0; t < 3; t++) {
                float wtk = wk[(o * 8 + ic) * 3 + t];
                float wtv = wv[(o * 8 + ic) * 3 + t];
                #pragma unroll
                for (int p = 0; p < 4; p++) {
                    acck[o][p] = fmaf(wtk, val[p + t], acck[o][p]);
                    accv[o][p] = fmaf(wtv, val[p + t], accv[o][p]);
                }
            }
    }
    #pragma unroll
    for (int o = 0; o < 8; o++) {
        #pragma unroll
        for (int p = 0; p < 4; p++)
            kT[((size_t)(o * 8 + h) * WW + w0 + p) * DH + jf] = f2bf(acck[o][p]);
        short4v pv;
        #pragma unroll
        for (int p = 0; p < 4; p++) pv[p] = (short)f2bf(accv[o][p]);
        *(short4v*)(v + ((size_t)o * F + f) * WW + w0) = pv;
    }
}

// ---------------------------------------------------------------------------
// Fused flash attention (unchanged from R1): no Qs LDS, early bias loads,
// pair-major XCD-friendly block mapping.
// ---------------------------------------------------------------------------
__global__ __launch_bounds__(256) void k_attn(
    const unsigned short* __restrict__ qT, const unsigned short* __restrict__ kT,
    const unsigned short* __restrict__ v,
    const float* __restrict__ a0, const float* __restrict__ a1,
    const float* __restrict__ a2, int nsrc,
    float* __restrict__ pq, unsigned short* __restrict__ aout)
{
    int pair = blockIdx.x & 63;          // phys mod 8 == pair mod 8 -> same XCD
    int qw0  = (blockIdx.x >> 6) << 6;

    __shared__ unsigned short Ks[64 * 136];   // [k][d], pad 8 -> row 272B
    __shared__ unsigned short Vt[128 * 72];   // [d][k-chunk], pad 8 -> row 144B
    __shared__ unsigned short P [64 * 72];    // [q][k-chunk], wave-private rows

    int tid = threadIdx.x;
    const unsigned short* qb = qT + ((size_t)pair * WW + qw0) * DH;
    const unsigned short* kb = kT + (size_t)pair * WW * DH;
    const unsigned short* vb = v  + (size_t)pair * DH * WW;

    int wv = tid >> 6, lane = tid & 63;
    int lr = lane & 15, lkg = lane >> 4;
    int qrow = qw0 + wv * 16 + lr;

    short8 bq[4];
    #pragma unroll
    for (int dk = 0; dk < 4; dk++)
        bq[dk] = *(const short8*)(qb + (size_t)(wv * 16 + lr) * DH + dk * 32 + lkg * 8);

    float4v acc[8] = {};
    float mrun = -1e30f, lrun = 0.f;
    const float scale = 0.08838834764831845f;   // 1/sqrt(128)
    size_t bbase = (size_t)pair * WW * WW + (size_t)qrow * WW;

    for (int kc = 0; kc < 8; kc++) {
        __syncthreads();   // prior chunk's Ks/Vt/P reads done

        float4v b0v[4], b1v[4], b2v[4];
        #pragma unroll
        for (int mi = 0; mi < 4; mi++)
            b0v[mi] = *(const float4v*)(a0 + bbase + kc * 64 + mi * 16 + lkg * 4);
        if (nsrc > 1) {
            #pragma unroll
            for (int mi = 0; mi < 4; mi++)
                b1v[mi] = *(const float4v*)(a1 + bbase + kc * 64 + mi * 16 + lkg * 4);
        }
        if (nsrc > 2) {
            #pragma unroll
            for (int mi = 0; mi < 4; mi++)
                b2v[mi] = *(const float4v*)(a2 + bbase + kc * 64 + mi * 16 + lkg * 4);
        }

        #pragma unroll
        for (int it = 0; it < 4; it++) {      // K chunk 64x128
            int idx = it * 256 + tid;
            int r = idx >> 4, c = idx & 15;
            *(short8*)(Ks + r * 136 + c * 8) =
                *(const short8*)(kb + (size_t)(kc * 64 + r) * DH + c * 8);
        }
        #pragma unroll
        for (int it = 0; it < 4; it++) {      // V chunk 128x64
            int idx = it * 256 + tid;
            int j = idx >> 3, c = idx & 7;
            *(short8*)(Vt + j * 72 + c * 8) =
                *(const short8*)(vb + (size_t)j * WW + kc * 64 + c * 8);
        }
        __syncthreads();

        // S^T: D[k 64][q 16-per-wave], contraction over d=128
        float4v sacc[4] = {};
        #pragma unroll
        for (int dk = 0; dk < 4; dk++) {
            short8 ak[4];
            #pragma unroll
            for (int mi = 0; mi < 4; mi++)
                ak[mi] = *(const short8*)(Ks + (mi * 16 + lr) * 136 + dk * 32 + lkg * 8);
            #pragma unroll
            for (int mi = 0; mi < 4; mi++)
                sacc[mi] = __builtin_amdgcn_mfma_f32_16x16x32_bf16(ak[mi], bq[dk], sacc[mi], 0, 0, 0);
        }

        float sv[4][4];
        float mx = -1e30f;
        #pragma unroll
        for (int mi = 0; mi < 4; mi++) {
            int k0 = kc * 64 + mi * 16 + lkg * 4;
            float4v s;
            #pragma unroll
            for (int r = 0; r < 4; r++) s[r] = sacc[mi][r] * scale + b0v[mi][r];
            if (nsrc > 1) {
                #pragma unroll
                for (int r = 0; r < 4; r++) s[r] += b1v[mi][r];
            }
            if (nsrc > 2) {
                #pragma unroll
                for (int r = 0; r < 4; r++) s[r] += b2v[mi][r];
            }
            *(float4v*)(pq + bbase + k0) = s;
            #pragma unroll
            for (int r = 0; r < 4; r++) { sv[mi][r] = s[r]; mx = fmaxf(mx, s[r]); }
        }
        mx = fmaxf(mx, __shfl_xor(mx, 16));
        mx = fmaxf(mx, __shfl_xor(mx, 32));
        float mnew  = fmaxf(mrun, mx);
        float alpha = __expf(mrun - mnew);
        float lsum  = 0.f;
        #pragma unroll
        for (int mi = 0; mi < 4; mi++) {
            short4v pk;
            #pragma unroll
            for (int r = 0; r < 4; r++) {
                float e = __expf(sv[mi][r] - mnew);
                lsum += e;
                pk[r] = (short)f2bf(e);
            }
            *(short4v*)(P + (wv * 16 + lr) * 72 + mi * 16 + lkg * 4) = pk;
        }
        lsum += __shfl_xor(lsum, 16);
        lsum += __shfl_xor(lsum, 32);
        lrun = lrun * alpha + lsum;
        mrun = mnew;

        #pragma unroll
        for (int mt = 0; mt < 8; mt++)
            #pragma unroll
            for (int r = 0; r < 4; r++) acc[mt][r] *= alpha;

        // PV: D[d 128][q 16], contraction over this 64-k chunk
        #pragma unroll
        for (int ks = 0; ks < 2; ks++) {
            short8 bp = *(const short8*)(P + (wv * 16 + lr) * 72 + ks * 32 + lkg * 8);
            #pragma unroll
            for (int mt = 0; mt < 8; mt++) {
                short8 av = *(const short8*)(Vt + (mt * 16 + lr) * 72 + ks * 32 + lkg * 8);
                acc[mt] = __builtin_amdgcn_mfma_f32_16x16x32_bf16(av, bp, acc[mt], 0, 0, 0);
            }
        }
    }

    float linv = 1.f / lrun;
    unsigned short* ab = aout + (size_t)pair * DH * WW + qw0 + wv * 16 + lr;
    #pragma unroll
    for (int mt = 0; mt < 8; mt++)
        #pragma unroll
        for (int r = 0; r < 4; r++) {
            int d = mt * 16 + lkg * 4 + r;
            ab[(size_t)d * WW] = f2bf(acc[mt][r] * linv);
        }
}

// ---------------------------------------------------------------------------
// wo conv: 1x3, 8->8, bf16 in (natural), fp32 out. 4 points/thread.
// ---------------------------------------------------------------------------
__global__ __launch_bounds__(256) void k_wo(
    const unsigned short* __restrict__ a, const float* __restrict__ w,
    float* __restrict__ z)
{
    int p0 = (blockIdx.x * 256 + threadIdx.x) * 4;
    int f = p0 >> 9, w0 = p0 & 511;
    float acc[8][4];
    #pragma unroll
    for (int o = 0; o < 8; o++)
        #pragma unroll
        for (int p = 0; p < 4; p++) acc[o][p] = 0.f;
    for (int ic = 0; ic < 8; ic++) {
        const unsigned short* s = a + ((size_t)ic * F + f) * WW;
        float val[6];
        #pragma unroll
        for (int i = 0; i < 6; i++) {
            int ww = w0 - 1 + i;
            val[i] = (ww >= 0 && ww < WW) ? bf2f(s[ww]) : 0.f;
        }
        #pragma unroll
        for (int o = 0; o < 8; o++)
            #pragma unroll
            for (int t = 0; t < 3; t++) {
                float wt = w[(o * 8 + ic) * 3 + t];
                #pragma unroll
                for (int p = 0; p < 4; p++) acc[o][p] = fmaf(wt, val[p + t], acc[o][p]);
            }
    }
    #pragma unroll
    for (int o = 0; o < 8; o++) {
        float4v ov;
        #pragma unroll
        for (int p = 0; p < 4; p++) ov[p] = acc[o][p];
        *(float4v*)(z + ((size_t)o * F + f) * WW + w0) = ov;
    }
}

// ---------------------------------------------------------------------------
extern "C" void kernel_launch(void* const* d_in, const int* in_sizes, int n_in,
                              void* d_out, int out_size, void* d_ws, size_t ws_size,
                              hipStream_t stream) {
    const float* x        = (const float*)d_in[0];
    const float* skip     = (const float*)d_in[1];
    const float* prev_qk1 = (const float*)d_in[2];
    const float* prev_qk2 = (const float*)d_in[3];
    const float* skip_qk  = (const float*)d_in[4];
    const float* g1  = (const float*)d_in[5];
    const float* b1  = (const float*)d_in[6];
    const float* wq1 = (const float*)d_in[7];
    const float* wk1 = (const float*)d_in[8];
    const float* wv1 = (const float*)d_in[9];
    const float* wo1 = (const float*)d_in[10];
    const float* g2  = (const float*)d_in[11];
    const float* b2  = (const float*)d_in[12];
    const float* wq2 = (const float*)d_in[13];
    const float* wk2 = (const float*)d_in[14];
    const float* wv2 = (const float*)d_in[15];
    const float* wo2 = (const float*)d_in[16];
    const float* g3  = (const float*)d_in[17];
    const float* b3  = (const float*)d_in[18];
    const float* wc1 = (const float*)d_in[19];
    const float* wc2 = (const float*)d_in[20];

    char* ws = (char*)d_ws;
    // Phase-overlapped workspace (peak ~101.2 MB):
    float*          z1 = (float*)(ws + 0);                   // 16.78MB  [A..C]
    float*          z2 = (float*)(ws + 16777216);            // 16.78MB  [B..C]
    // Region R: attn phase layout
    unsigned short* qT = (unsigned short*)(ws + 33554432);   //  8.39MB
    unsigned short* kT = (unsigned short*)(ws + 41943040);   //  8.39MB
    unsigned short* vB = (unsigned short*)(ws + 50331648);   //  8.39MB
    unsigned short* nh = (unsigned short*)(ws + 58720256);   // 16.78MB (ln1/ln2 out)
    unsigned short* aB = (unsigned short*)(ws + 75497472);   //  8.39MB
    // Region R: MLP phase layout (aliases the above; attn bufs dead by then)
    unsigned short* nh3p = (unsigned short*)(ws + 33554432); // 33.75MB [PF][PW][32] bf16
    unsigned short* tBp  = (unsigned short*)(ws + 67305728); // 33.75MB
    unsigned short* A1p  = (unsigned short*)(ws + 101057024);// 18KB
    unsigned short* A2p  = (unsigned short*)(ws + 101075456);//  9KB
    float*          mu3  = (float*)(ws + 101084672);         // 48KB
    float*          rs3  = (float*)(ws + 101133824);         // 48KB

    float* out0 = (float*)d_out;
    float* pq1  = out0 + 4194304;
    float* pq2  = pq1 + 16777216;

    k_prep<<<36, 256, 0, stream>>>(wc1, wc2, A1p, A2p);

    // --- attn1: x -> ln1 -> qkv -> fused(QK^T + prev_qk1+skip_qk -> pq1, softmax.V) -> wo
    k_ln  <<<8 * 32,  256, 0, stream>>>(x, nullptr, nullptr, g1, b1, nh);
    k_qkv <<<512,     256, 0, stream>>>(nh, 8, wq1, nh, 1, wk1, wv1, qT, kT, vB);
    k_attn<<<512,     256, 0, stream>>>(qT, kT, vB, prev_qk1, skip_qk, nullptr, 2, pq1, aB);
    k_wo  <<<512,     256, 0, stream>>>(aB, wo1, z1);

    // --- attn2: [x,z1] -> ln2 -> q ; k,v from raw skip ; pq2 = qk2 + skip_qk+pq1+prev_qk2
    k_ln  <<<16 * 32, 256, 0, stream>>>(x, z1, nullptr, g2, b2, nh);
    k_qkv <<<512,     256, 0, stream>>>(nh, 16, wq2, skip, 0, wk2, wv2, qT, kT, vB);
    k_attn<<<512,     256, 0, stream>>>(qT, kT, vB, skip_qk, pq1, prev_qk2, 3, pq2, aB);
    k_wo  <<<512,     256, 0, stream>>>(aB, wo2, z2);

    // --- MLP: ln3([x,z1,z2]) channel-last -> MFMA conv3x3(24->32) -> sqrelu
    //          -> MFMA conv3x3(32->8) + x.  (attn buffers dead; region aliased)
    k_pad      <<<13,      256, 0, stream>>>(nh3p, tBp);
    k_ln3_stats<<<24 * 32, 256, 0, stream>>>(x, z1, z2, mu3, rs3);
    k_ln3_apply<<<2048,    256, 0, stream>>>(x, z1, z2, mu3, rs3, g3, b3, nh3p);
    k_conv1m   <<<2048,    256, 0, stream>>>(nh3p, A1p, tBp);
    k_conv2m   <<<2048,    256, 0, stream>>>(tBp, A2p, x, out0);
}

// Round 3
// 689.675 us; speedup vs baseline: 1.2995x; 1.1181x over previous
//
#include <hip/hip_runtime.h>
#include <hip/hip_bf16.h>

// Problem constants
#define F    1024
#define WW   512
#define DH   128          // head dim
#define NPAIR 64          // OC(8) * heads(8)
#define PW   514          // padded width  (512 + 2)
#define PF   1026         // padded height (1024 + 2)

using short8  = __attribute__((ext_vector_type(8))) short;   // 8 bf16 (4 VGPRs)
using short4v = __attribute__((ext_vector_type(4))) short;   // 4 bf16 (8B)
using float4v = __attribute__((ext_vector_type(4))) float;   // MFMA C/D frag

__device__ __forceinline__ float bf2f(unsigned short u) {
    union { unsigned int i; float f; } x; x.i = ((unsigned int)u) << 16; return x.f;
}
__device__ __forceinline__ unsigned short f2bf(float f) {
    union { float f; unsigned int i; } x; x.f = f;
    unsigned int r = x.i + 0x7fff + ((x.i >> 16) & 1);   // RNE
    return (unsigned short)(r >> 16);
}

// ---------------------------------------------------------------------------
// LayerNorm over F axis per (c,w); virtual concat of up to 2 fp32 sources
// (8 channels each). out: bf16 (C, F, W) channel-first (attn path).
// grid = C*32, block 256 (16w x 16f).
// ---------------------------------------------------------------------------
__global__ __launch_bounds__(256) void k_ln(
    const float* __restrict__ s0, const float* __restrict__ s1,
    const float* __restrict__ s2,
    const float* __restrict__ g, const float* __restrict__ b,
    unsigned short* __restrict__ out)
{
    int c  = blockIdx.x >> 5;
    int w0 = (blockIdx.x & 31) << 4;
    const float* src = (c < 8) ? s0 : (c < 16) ? s1 : s2;
    src += (size_t)(c & 7) * F * WW;
    int tx = threadIdx.x & 15, ty = threadIdx.x >> 4;

    float sum = 0.f, ssq = 0.f;
    for (int f = ty; f < F; f += 16) {
        float v = src[f * WW + w0 + tx];
        sum += v; ssq += v * v;
    }
    __shared__ float sm[16][17], sq[16][17];
    __shared__ float mu_s[16], rs_s[16];
    sm[ty][tx] = sum; sq[ty][tx] = ssq;
    __syncthreads();
    if (threadIdx.x < 16) {
        float s = 0.f, q = 0.f;
        #pragma unroll
        for (int i = 0; i < 16; i++) { s += sm[i][threadIdx.x]; q += sq[i][threadIdx.x]; }
        float mu  = s * (1.f / F);
        float var = q * (1.f / F) - mu * mu;     // biased var (jnp.var)
        mu_s[threadIdx.x] = mu;
        rs_s[threadIdx.x] = rsqrtf(var + 1e-8f);
    }
    __syncthreads();
    float mu = mu_s[tx], rs = rs_s[tx];
    unsigned short* o = out + (size_t)c * F * WW;
    for (int f = ty; f < F; f += 16) {
        float v = src[f * WW + w0 + tx];
        float r = (v - mu) * rs * g[c * F + f] + b[c * F + f];
        o[f * WW + w0 + tx] = f2bf(r);
    }
}

// ---------------------------------------------------------------------------
// LN3 stats: mu/rsigma per (c,w) over F, 24 channels from x,z1,z2.
// ---------------------------------------------------------------------------
__global__ __launch_bounds__(256) void k_ln3_stats(
    const float* __restrict__ s0, const float* __restrict__ s1,
    const float* __restrict__ s2,
    float* __restrict__ mu3, float* __restrict__ rs3)
{
    int c  = blockIdx.x >> 5;
    int w0 = (blockIdx.x & 31) << 4;
    const float* src = (c < 8) ? s0 : (c < 16) ? s1 : s2;
    src += (size_t)(c & 7) * F * WW;
    int tx = threadIdx.x & 15, ty = threadIdx.x >> 4;

    float sum = 0.f, ssq = 0.f;
    for (int f = ty; f < F; f += 16) {
        float v = src[f * WW + w0 + tx];
        sum += v; ssq += v * v;
    }
    __shared__ float sm[16][17], sq[16][17];
    sm[ty][tx] = sum; sq[ty][tx] = ssq;
    __syncthreads();
    if (threadIdx.x < 16) {
        float s = 0.f, q = 0.f;
        #pragma unroll
        for (int i = 0; i < 16; i++) { s += sm[i][threadIdx.x]; q += sq[i][threadIdx.x]; }
        float mu  = s * (1.f / F);
        float var = q * (1.f / F) - mu * mu;
        mu3[c * WW + w0 + threadIdx.x] = mu;
        rs3[c * WW + w0 + threadIdx.x] = rsqrtf(var + 1e-8f);
    }
}

// ---------------------------------------------------------------------------
// LN3 apply: write nh3p channel-last padded [PF][PW][32] bf16; interior only.
// ---------------------------------------------------------------------------
__global__ __launch_bounds__(256) void k_ln3_apply(
    const float* __restrict__ s0, const float* __restrict__ s1,
    const float* __restrict__ s2,
    const float* __restrict__ mu3, const float* __restrict__ rs3,
    const float* __restrict__ g, const float* __restrict__ b,
    unsigned short* __restrict__ outp)
{
    int p = blockIdx.x * 256 + threadIdx.x;
    int f = p >> 9, w = p & 511;
    unsigned short buf[32];
    #pragma unroll
    for (int c = 0; c < 24; c++) {
        const float* src = (c < 8) ? s0 : (c < 16) ? s1 : s2;
        float v = src[((size_t)(c & 7) * F + f) * WW + w];
        float r = (v - mu3[c * WW + w]) * rs3[c * WW + w] * g[c * F + f] + b[c * F + f];
        buf[c] = f2bf(r);
    }
    #pragma unroll
    for (int c = 24; c < 32; c++) buf[c] = 0;
    unsigned short* op = outp + ((size_t)(f + 1) * PW + (w + 1)) * 32;
    #pragma unroll
    for (int q = 0; q < 4; q++) *(short8*)(op + q * 8) = *(const short8*)(buf + q * 8);
}

// ---------------------------------------------------------------------------
// Zero the spatial pad cells of the two padded channel-last buffers.
// ---------------------------------------------------------------------------
__global__ void k_pad(unsigned short* __restrict__ a, unsigned short* __restrict__ b)
{
    int i = blockIdx.x * 256 + threadIdx.x;
    if (i >= 3076) return;
    int f, w;
    if (i < 514)       { f = 0;    w = i; }
    else if (i < 1028) { f = 1025; w = i - 514; }
    else { int j = i - 1028; f = 1 + (j >> 1); w = (j & 1) ? 513 : 0; }
    size_t off = ((size_t)f * PW + w) * 32;
    short8 z = {};
    #pragma unroll
    for (int q = 0; q < 4; q++) {
        *(short8*)(a + off + q * 8) = z;
        *(short8*)(b + off + q * 8) = z;
    }
}

// ---------------------------------------------------------------------------
// Weight prep: pack conv weights as bf16 MFMA A-fragments.
// ---------------------------------------------------------------------------
__global__ void k_prep(const float* __restrict__ wc1, const float* __restrict__ wc2,
                       unsigned short* __restrict__ A1, unsigned short* __restrict__ A2)
{
    int i = blockIdx.x * 256 + threadIdx.x;
    if (i < 9216) {
        int ic = i & 31, row = i >> 5;       // row 0..287
        int o16 = row & 15, tm = row >> 4;   // tm 0..17
        int tap = tm >> 1, m = tm & 1;
        int oc = m * 16 + o16;
        A1[i] = (ic < 24) ? f2bf(wc1[(oc * 24 + ic) * 9 + tap]) : (unsigned short)0;
    }
    if (i < 4608) {
        int ic = i & 31, row = i >> 5;       // 0..143
        int o = row & 15, tap = row >> 4;
        A2[i] = (o < 8) ? f2bf(wc2[(o * 32 + ic) * 9 + tap]) : (unsigned short)0;
    }
}

// ---------------------------------------------------------------------------
// conv1 via implicit-GEMM MFMA: 24(->32)ch -> 32ch, 3x3, + SquaredReLU.
// ---------------------------------------------------------------------------
__global__ __launch_bounds__(256) void k_conv1m(
    const unsigned short* __restrict__ inp, const unsigned short* __restrict__ A1,
    unsigned short* __restrict__ outp)
{
    int wv = threadIdx.x >> 6, lane = threadIdx.x & 63;
    int lr = lane & 15, lkg = lane >> 4;

    short8 a[9][2];
    #pragma unroll
    for (int tap = 0; tap < 9; tap++)
        #pragma unroll
        for (int m = 0; m < 2; m++)
            a[tap][m] = *(const short8*)(A1 + ((tap * 2 + m) * 16 + lr) * 32 + lkg * 8);

    int f = blockIdx.x >> 1;
    int half = blockIdx.x & 1;
    for (int it = 0; it < 4; it++) {
        int w0 = (half * 16 + wv * 4 + it) * 16;
        float4v acc0 = {}, acc1 = {};
        #pragma unroll
        for (int dy = 0; dy < 3; dy++)
            #pragma unroll
            for (int dx = 0; dx < 3; dx++) {
                short8 bfrag = *(const short8*)(inp +
                    ((size_t)(f + dy) * PW + (w0 + lr + dx)) * 32 + lkg * 8);
                acc0 = __builtin_amdgcn_mfma_f32_16x16x32_bf16(a[dy*3+dx][0], bfrag, acc0, 0, 0, 0);
                acc1 = __builtin_amdgcn_mfma_f32_16x16x32_bf16(a[dy*3+dx][1], bfrag, acc1, 0, 0, 0);
            }
        unsigned short* op = outp + ((size_t)(f + 1) * PW + (w0 + lr + 1)) * 32;
        short4v o0, o1;
        #pragma unroll
        for (int r = 0; r < 4; r++) {
            float v0 = fmaxf(acc0[r], 0.f);
            float v1 = fmaxf(acc1[r], 0.f);
            o0[r] = (short)f2bf(v0 * v0);
            o1[r] = (short)f2bf(v1 * v1);
        }
        *(short4v*)(op + lkg * 4)      = o0;   // oc 0..15
        *(short4v*)(op + 16 + lkg * 4) = o1;   // oc 16..31
    }
}

// ---------------------------------------------------------------------------
// conv2 via implicit-GEMM MFMA: 32ch -> 8ch (pad 16), 3x3, + residual x.
// ---------------------------------------------------------------------------
__global__ __launch_bounds__(256) void k_conv2m(
    const unsigned short* __restrict__ inp, const unsigned short* __restrict__ A2,
    const float* __restrict__ x, float* __restrict__ out)
{
    int wv = threadIdx.x >> 6, lane = threadIdx.x & 63;
    int lr = lane & 15, lkg = lane >> 4;

    short8 a[9];
    #pragma unroll
    for (int tap = 0; tap < 9; tap++)
        a[tap] = *(const short8*)(A2 + (tap * 16 + lr) * 32 + lkg * 8);

    int f = blockIdx.x >> 1;
    int half = blockIdx.x & 1;
    for (int it = 0; it < 4; it++) {
        int w0 = (half * 16 + wv * 4 + it) * 16;
        float4v acc = {};
        #pragma unroll
        for (int dy = 0; dy < 3; dy++)
            #pragma unroll
            for (int dx = 0; dx < 3; dx++) {
                short8 bfrag = *(const short8*)(inp +
                    ((size_t)(f + dy) * PW + (w0 + lr + dx)) * 32 + lkg * 8);
                acc = __builtin_amdgcn_mfma_f32_16x16x32_bf16(a[dy*3+dx], bfrag, acc, 0, 0, 0);
            }
        if (lkg < 2) {
            #pragma unroll
            for (int r = 0; r < 4; r++) {
                int oc = lkg * 4 + r;
                size_t off = ((size_t)oc * F + f) * WW + w0 + lr;
                out[off] = x[off] + acc[r];
            }
        }
    }
}

// ---------------------------------------------------------------------------
// 1x3 conv along W producing q,k,v (8 out-ch each), ALL in natural layout
// [oc][f][w] bf16, fully coalesced short4v stores (no partial lines).
// ---------------------------------------------------------------------------
__global__ __launch_bounds__(256) void k_qkv(
    const unsigned short* __restrict__ srcQ, int CinQ, const float* __restrict__ wq,
    const void* __restrict__ srcKV, int kvBf16,
    const float* __restrict__ wk, const float* __restrict__ wv,
    unsigned short* __restrict__ qN, unsigned short* __restrict__ kN,
    unsigned short* __restrict__ v)
{
    int p0 = (blockIdx.x * 256 + threadIdx.x) * 4;
    int f  = p0 >> 9;
    int w0 = p0 & 511;

    // ---- Q ----
    float accq[8][4];
    #pragma unroll
    for (int o = 0; o < 8; o++) { accq[o][0]=0.f; accq[o][1]=0.f; accq[o][2]=0.f; accq[o][3]=0.f; }
    for (int ic = 0; ic < CinQ; ic++) {
        const unsigned short* s = srcQ + ((size_t)ic * F + f) * WW;
        float val[6];
        #pragma unroll
        for (int i = 0; i < 6; i++) {
            int w = w0 - 1 + i;
            val[i] = (w >= 0 && w < WW) ? bf2f(s[w]) : 0.f;
        }
        #pragma unroll
        for (int o = 0; o < 8; o++)
            #pragma unroll
            for (int t = 0; t < 3; t++) {
                float wt = wq[(o * CinQ + ic) * 3 + t];
                #pragma unroll
                for (int p = 0; p < 4; p++) accq[o][p] = fmaf(wt, val[p + t], accq[o][p]);
            }
    }
    #pragma unroll
    for (int o = 0; o < 8; o++) {
        short4v t;
        #pragma unroll
        for (int p = 0; p < 4; p++) t[p] = (short)f2bf(accq[o][p]);
        *(short4v*)(qN + ((size_t)o * F + f) * WW + w0) = t;
    }

    // ---- K and V (8 in-ch always) ----
    float acck[8][4], accv[8][4];
    #pragma unroll
    for (int o = 0; o < 8; o++)
        #pragma unroll
        for (int p = 0; p < 4; p++) { acck[o][p] = 0.f; accv[o][p] = 0.f; }
    for (int ic = 0; ic < 8; ic++) {
        float val[6];
        if (kvBf16) {
            const unsigned short* s = (const unsigned short*)srcKV + ((size_t)ic * F + f) * WW;
            #pragma unroll
            for (int i = 0; i < 6; i++) {
                int w = w0 - 1 + i;
                val[i] = (w >= 0 && w < WW) ? bf2f(s[w]) : 0.f;
            }
        } else {
            const float* s = (const float*)srcKV + ((size_t)ic * F + f) * WW;
            #pragma unroll
            for (int i = 0; i < 6; i++) {
                int w = w0 - 1 + i;
                val[i] = (w >= 0 && w < WW) ? s[w] : 0.f;
            }
        }
        #pragma unroll
        for (int o = 0; o < 8; o++)
            #pragma unroll
            for (int t = 0; t < 3; t++) {
                float wtk = wk[(o * 8 + ic) * 3 + t];
                float wtv = wv[(o * 8 + ic) * 3 + t];
                #pragma unroll
                for (int p = 0; p < 4; p++) {
                    acck[o][p] = fmaf(wtk, val[p + t], acck[o][p]);
                    accv[o][p] = fmaf(wtv, val[p + t], accv[o][p]);
                }
            }
    }
    #pragma unroll
    for (int o = 0; o < 8; o++) {
        short4v tk, tv;
        #pragma unroll
        for (int p = 0; p < 4; p++) { tk[p] = (short)f2bf(acck[o][p]); tv[p] = (short)f2bf(accv[o][p]); }
        *(short4v*)(kN + ((size_t)o * F + f) * WW + w0) = tk;
        *(short4v*)(v  + ((size_t)o * F + f) * WW + w0) = tv;
    }
}

// ---------------------------------------------------------------------------
// Transpose q,k natural [oc][f][w] -> [pair][w][jf] (pair = oc*8 + f>>7,
// jf = f&127) via LDS tile 128jf x 64w, pitch 66 (conflict-free column reads:
// bank = jf*33 + w/2 mod 32, all distinct). Global writes assemble FULL 64B
// lines per instruction (16 w x 64B). grid = 64 pairs * 8 w-tiles = 512.
// ---------------------------------------------------------------------------
__global__ __launch_bounds__(256) void k_tr(
    const unsigned short* __restrict__ qN, const unsigned short* __restrict__ kN,
    unsigned short* __restrict__ qT, unsigned short* __restrict__ kT)
{
    __shared__ unsigned short T[128 * 66];
    int pair = blockIdx.x >> 3, wt = blockIdx.x & 7;
    int o = pair >> 3, h = pair & 7;
    int tid = threadIdx.x;
    int wvv = tid >> 6, lane = tid & 63;
    int w_l = lane & 15, jq4 = lane >> 4;

    #pragma unroll
    for (int s = 0; s < 2; s++) {
        const unsigned short* src = (s == 0 ? qN : kN) +
            ((size_t)o * F + h * 128) * WW + wt * 64;
        unsigned short* dst = (s == 0 ? qT : kT) +
            ((size_t)pair * WW + wt * 64 + wvv * 16 + w_l) * DH;
        if (s) __syncthreads();          // protect T reuse across passes
        #pragma unroll
        for (int it = 0; it < 4; it++) {
            int idx = it * 256 + tid;
            int r = idx >> 3, c = idx & 7;
            *(short8*)(T + r * 66 + c * 8) = *(const short8*)(src + (size_t)r * WW + c * 8);
        }
        __syncthreads();
        int wcol = wvv * 16 + w_l;
        #pragma unroll
        for (int jq = 0; jq < 4; jq++) {
            int jfg = jq * 4 + jq4;
            short8 vv;
            #pragma unroll
            for (int i = 0; i < 8; i++)
                vv[i] = (short)T[(jfg * 8 + i) * 66 + wcol];
            *(short8*)(dst + jfg * 8) = vv;
        }
    }
}

// ---------------------------------------------------------------------------
// Fused flash attention (unchanged): no Qs LDS, early bias loads,
// pair-major XCD-friendly block mapping.
// ---------------------------------------------------------------------------
__global__ __launch_bounds__(256) void k_attn(
    const unsigned short* __restrict__ qT, const unsigned short* __restrict__ kT,
    const unsigned short* __restrict__ v,
    const float* __restrict__ a0, const float* __restrict__ a1,
    const float* __restrict__ a2, int nsrc,
    float* __restrict__ pq, unsigned short* __restrict__ aout)
{
    int pair = blockIdx.x & 63;          // phys mod 8 == pair mod 8 -> same XCD
    int qw0  = (blockIdx.x >> 6) << 6;

    __shared__ unsigned short Ks[64 * 136];   // [k][d], pad 8 -> row 272B
    __shared__ unsigned short Vt[128 * 72];   // [d][k-chunk], pad 8 -> row 144B
    __shared__ unsigned short P [64 * 72];    // [q][k-chunk], wave-private rows

    int tid = threadIdx.x;
    const unsigned short* qb = qT + ((size_t)pair * WW + qw0) * DH;
    const unsigned short* kb = kT + (size_t)pair * WW * DH;
    const unsigned short* vb = v  + (size_t)pair * DH * WW;

    int wv = tid >> 6, lane = tid & 63;
    int lr = lane & 15, lkg = lane >> 4;
    int qrow = qw0 + wv * 16 + lr;

    short8 bq[4];
    #pragma unroll
    for (int dk = 0; dk < 4; dk++)
        bq[dk] = *(const short8*)(qb + (size_t)(wv * 16 + lr) * DH + dk * 32 + lkg * 8);

    float4v acc[8] = {};
    float mrun = -1e30f, lrun = 0.f;
    const float scale = 0.08838834764831845f;   // 1/sqrt(128)
    size_t bbase = (size_t)pair * WW * WW + (size_t)qrow * WW;

    for (int kc = 0; kc < 8; kc++) {
        __syncthreads();   // prior chunk's Ks/Vt/P reads done

        float4v b0v[4], b1v[4], b2v[4];
        #pragma unroll
        for (int mi = 0; mi < 4; mi++)
            b0v[mi] = *(const float4v*)(a0 + bbase + kc * 64 + mi * 16 + lkg * 4);
        if (nsrc > 1) {
            #pragma unroll
            for (int mi = 0; mi < 4; mi++)
                b1v[mi] = *(const float4v*)(a1 + bbase + kc * 64 + mi * 16 + lkg * 4);
        }
        if (nsrc > 2) {
            #pragma unroll
            for (int mi = 0; mi < 4; mi++)
                b2v[mi] = *(const float4v*)(a2 + bbase + kc * 64 + mi * 16 + lkg * 4);
        }

        #pragma unroll
        for (int it = 0; it < 4; it++) {      // K chunk 64x128
            int idx = it * 256 + tid;
            int r = idx >> 4, c = idx & 15;
            *(short8*)(Ks + r * 136 + c * 8) =
                *(const short8*)(kb + (size_t)(kc * 64 + r) * DH + c * 8);
        }
        #pragma unroll
        for (int it = 0; it < 4; it++) {      // V chunk 128x64
            int idx = it * 256 + tid;
            int j = idx >> 3, c = idx & 7;
            *(short8*)(Vt + j * 72 + c * 8) =
                *(const short8*)(vb + (size_t)j * WW + kc * 64 + c * 8);
        }
        __syncthreads();

        // S^T: D[k 64][q 16-per-wave], contraction over d=128
        float4v sacc[4] = {};
        #pragma unroll
        for (int dk = 0; dk < 4; dk++) {
            short8 ak[4];
            #pragma unroll
            for (int mi = 0; mi < 4; mi++)
                ak[mi] = *(const short8*)(Ks + (mi * 16 + lr) * 136 + dk * 32 + lkg * 8);
            #pragma unroll
            for (int mi = 0; mi < 4; mi++)
                sacc[mi] = __builtin_amdgcn_mfma_f32_16x16x32_bf16(ak[mi], bq[dk], sacc[mi], 0, 0, 0);
        }

        float sv[4][4];
        float mx = -1e30f;
        #pragma unroll
        for (int mi = 0; mi < 4; mi++) {
            int k0 = kc * 64 + mi * 16 + lkg * 4;
            float4v s;
            #pragma unroll
            for (int r = 0; r < 4; r++) s[r] = sacc[mi][r] * scale + b0v[mi][r];
            if (nsrc > 1) {
                #pragma unroll
                for (int r = 0; r < 4; r++) s[r] += b1v[mi][r];
            }
            if (nsrc > 2) {
                #pragma unroll
                for (int r = 0; r < 4; r++) s[r] += b2v[mi][r];
            }
            *(float4v*)(pq + bbase + k0) = s;
            #pragma unroll
            for (int r = 0; r < 4; r++) { sv[mi][r] = s[r]; mx = fmaxf(mx, s[r]); }
        }
        mx = fmaxf(mx, __shfl_xor(mx, 16));
        mx = fmaxf(mx, __shfl_xor(mx, 32));
        float mnew  = fmaxf(mrun, mx);
        float alpha = __expf(mrun - mnew);
        float lsum  = 0.f;
        #pragma unroll
        for (int mi = 0; mi < 4; mi++) {
            short4v pk;
            #pragma unroll
            for (int r = 0; r < 4; r++) {
                float e = __expf(sv[mi][r] - mnew);
                lsum += e;
                pk[r] = (short)f2bf(e);
            }
            *(short4v*)(P + (wv * 16 + lr) * 72 + mi * 16 + lkg * 4) = pk;
        }
        lsum += __shfl_xor(lsum, 16);
        lsum += __shfl_xor(lsum, 32);
        lrun = lrun * alpha + lsum;
        mrun = mnew;

        #pragma unroll
        for (int mt = 0; mt < 8; mt++)
            #pragma unroll
            for (int r = 0; r < 4; r++) acc[mt][r] *= alpha;

        // PV: D[d 128][q 16], contraction over this 64-k chunk
        #pragma unroll
        for (int ks = 0; ks < 2; ks++) {
            short8 bp = *(const short8*)(P + (wv * 16 + lr) * 72 + ks * 32 + lkg * 8);
            #pragma unroll
            for (int mt = 0; mt < 8; mt++) {
                short8 av = *(const short8*)(Vt + (mt * 16 + lr) * 72 + ks * 32 + lkg * 8);
                acc[mt] = __builtin_amdgcn_mfma_f32_16x16x32_bf16(av, bp, acc[mt], 0, 0, 0);
            }
        }
    }

    float linv = 1.f / lrun;
    unsigned short* ab = aout + (size_t)pair * DH * WW + qw0 + wv * 16 + lr;
    #pragma unroll
    for (int mt = 0; mt < 8; mt++)
        #pragma unroll
        for (int r = 0; r < 4; r++) {
            int d = mt * 16 + lkg * 4 + r;
            ab[(size_t)d * WW] = f2bf(acc[mt][r] * linv);
        }
}

// ---------------------------------------------------------------------------
// wo conv: 1x3, 8->8, bf16 in (natural), fp32 out. 4 points/thread.
// ---------------------------------------------------------------------------
__global__ __launch_bounds__(256) void k_wo(
    const unsigned short* __restrict__ a, const float* __restrict__ w,
    float* __restrict__ z)
{
    int p0 = (blockIdx.x * 256 + threadIdx.x) * 4;
    int f = p0 >> 9, w0 = p0 & 511;
    float acc[8][4];
    #pragma unroll
    for (int o = 0; o < 8; o++)
        #pragma unroll
        for (int p = 0; p < 4; p++) acc[o][p] = 0.f;
    for (int ic = 0; ic < 8; ic++) {
        const unsigned short* s = a + ((size_t)ic * F + f) * WW;
        float val[6];
        #pragma unroll
        for (int i = 0; i < 6; i++) {
            int ww = w0 - 1 + i;
            val[i] = (ww >= 0 && ww < WW) ? bf2f(s[ww]) : 0.f;
        }
        #pragma unroll
        for (int o = 0; o < 8; o++)
            #pragma unroll
            for (int t = 0; t < 3; t++) {
                float wt = w[(o * 8 + ic) * 3 + t];
                #pragma unroll
                for (int p = 0; p < 4; p++) acc[o][p] = fmaf(wt, val[p + t], acc[o][p]);
            }
    }
    #pragma unroll
    for (int o = 0; o < 8; o++) {
        float4v ov;
        #pragma unroll
        for (int p = 0; p < 4; p++) ov[p] = acc[o][p];
        *(float4v*)(z + ((size_t)o * F + f) * WW + w0) = ov;
    }
}

// ---------------------------------------------------------------------------
extern "C" void kernel_launch(void* const* d_in, const int* in_sizes, int n_in,
                              void* d_out, int out_size, void* d_ws, size_t ws_size,
                              hipStream_t stream) {
    const float* x        = (const float*)d_in[0];
    const float* skip     = (const float*)d_in[1];
    const float* prev_qk1 = (const float*)d_in[2];
    const float* prev_qk2 = (const float*)d_in[3];
    const float* skip_qk  = (const float*)d_in[4];
    const float* g1  = (const float*)d_in[5];
    const float* b1  = (const float*)d_in[6];
    const float* wq1 = (const float*)d_in[7];
    const float* wk1 = (const float*)d_in[8];
    const float* wv1 = (const float*)d_in[9];
    const float* wo1 = (const float*)d_in[10];
    const float* g2  = (const float*)d_in[11];
    const float* b2  = (const float*)d_in[12];
    const float* wq2 = (const float*)d_in[13];
    const float* wk2 = (const float*)d_in[14];
    const float* wv2 = (const float*)d_in[15];
    const float* wo2 = (const float*)d_in[16];
    const float* g3  = (const float*)d_in[17];
    const float* b3  = (const float*)d_in[18];
    const float* wc1 = (const float*)d_in[19];
    const float* wc2 = (const float*)d_in[20];

    char* ws = (char*)d_ws;
    // Phase-overlapped workspace (peak ~101.2 MB):
    float*          z1 = (float*)(ws + 0);                   // 16.78MB
    float*          z2 = (float*)(ws + 16777216);            // 16.78MB
    // Region R: attn phase layout
    unsigned short* qT = (unsigned short*)(ws + 33554432);   //  8.39MB [pair][w][jf]
    unsigned short* kT = (unsigned short*)(ws + 41943040);   //  8.39MB
    unsigned short* vB = (unsigned short*)(ws + 50331648);   //  8.39MB natural
    unsigned short* nh = (unsigned short*)(ws + 58720256);   // 16.78MB (ln1/ln2 out)
    unsigned short* aB = (unsigned short*)(ws + 75497472);   //  8.39MB
    unsigned short* qN = (unsigned short*)(ws + 83886080);   //  8.39MB natural q
    unsigned short* kN = (unsigned short*)(ws + 92274688);   //  8.39MB natural k
    // Region R: MLP phase layout (aliases the above; attn bufs dead by then)
    unsigned short* nh3p = (unsigned short*)(ws + 33554432); // 33.75MB [PF][PW][32] bf16
    unsigned short* tBp  = (unsigned short*)(ws + 67305728); // 33.75MB
    unsigned short* A1p  = (unsigned short*)(ws + 101057024);// 18KB
    unsigned short* A2p  = (unsigned short*)(ws + 101075456);//  9KB
    float*          mu3  = (float*)(ws + 101084672);         // 48KB
    float*          rs3  = (float*)(ws + 101133824);         // 48KB

    float* out0 = (float*)d_out;
    float* pq1  = out0 + 4194304;
    float* pq2  = pq1 + 16777216;

    k_prep<<<36, 256, 0, stream>>>(wc1, wc2, A1p, A2p);

    // --- attn1: x -> ln1 -> qkv(nat) -> transpose -> fused attn -> wo
    k_ln  <<<8 * 32,  256, 0, stream>>>(x, nullptr, nullptr, g1, b1, nh);
    k_qkv <<<512,     256, 0, stream>>>(nh, 8, wq1, nh, 1, wk1, wv1, qN, kN, vB);
    k_tr  <<<512,     256, 0, stream>>>(qN, kN, qT, kT);
    k_attn<<<512,     256, 0, stream>>>(qT, kT, vB, prev_qk1, skip_qk, nullptr, 2, pq1, aB);
    k_wo  <<<512,     256, 0, stream>>>(aB, wo1, z1);

    // --- attn2: [x,z1] -> ln2 -> q ; k,v from raw skip
    k_ln  <<<16 * 32, 256, 0, stream>>>(x, z1, nullptr, g2, b2, nh);
    k_qkv <<<512,     256, 0, stream>>>(nh, 16, wq2, skip, 0, wk2, wv2, qN, kN, vB);
    k_tr  <<<512,     256, 0, stream>>>(qN, kN, qT, kT);
    k_attn<<<512,     256, 0, stream>>>(qT, kT, vB, skip_qk, pq1, prev_qk2, 3, pq2, aB);
    k_wo  <<<512,     256, 0, stream>>>(aB, wo2, z2);

    // --- MLP: ln3([x,z1,z2]) channel-last -> MFMA conv3x3(24->32) -> sqrelu
    //          -> MFMA conv3x3(32->8) + x.
    k_pad      <<<13,      256, 0, stream>>>(nh3p, tBp);
    k_ln3_stats<<<24 * 32, 256, 0, stream>>>(x, z1, z2, mu3, rs3);
    k_ln3_apply<<<2048,    256, 0, stream>>>(x, z1, z2, mu3, rs3, g3, b3, nh3p);
    k_conv1m   <<<2048,    256, 0, stream>>>(nh3p, A1p, tBp);
    k_conv2m   <<<2048,    256, 0, stream>>>(tBp, A2p, x, out0);
}

// Round 4
// 673.187 us; speedup vs baseline: 1.3313x; 1.0245x over previous
//
#include <hip/hip_runtime.h>
#include <hip/hip_bf16.h>

// Problem constants
#define F    1024
#define WW   512
#define DH   128          // head dim
#define NPAIR 64          // OC(8) * heads(8)
#define PW   514          // padded width  (512 + 2)
#define PF   1026         // padded height (1024 + 2)

using short8  = __attribute__((ext_vector_type(8))) short;   // 8 bf16 (4 VGPRs)
using short4v = __attribute__((ext_vector_type(4))) short;   // 4 bf16 (8B)
using float4v = __attribute__((ext_vector_type(4))) float;   // MFMA C/D frag

__device__ __forceinline__ float bf2f(unsigned short u) {
    union { unsigned int i; float f; } x; x.i = ((unsigned int)u) << 16; return x.f;
}
__device__ __forceinline__ unsigned short f2bf(float f) {
    union { float f; unsigned int i; } x; x.f = f;
    unsigned int r = x.i + 0x7fff + ((x.i >> 16) & 1);   // RNE
    return (unsigned short)(r >> 16);
}

// ---------------------------------------------------------------------------
// LayerNorm over F axis per (c,w); virtual concat of up to 2 fp32 sources
// (8 channels each). out: bf16 (C, F, W) channel-first (attn path).
// grid = C*32, block 256 (16w x 16f).
// ---------------------------------------------------------------------------
__global__ __launch_bounds__(256) void k_ln(
    const float* __restrict__ s0, const float* __restrict__ s1,
    const float* __restrict__ s2,
    const float* __restrict__ g, const float* __restrict__ b,
    unsigned short* __restrict__ out)
{
    int c  = blockIdx.x >> 5;
    int w0 = (blockIdx.x & 31) << 4;
    const float* src = (c < 8) ? s0 : (c < 16) ? s1 : s2;
    src += (size_t)(c & 7) * F * WW;
    int tx = threadIdx.x & 15, ty = threadIdx.x >> 4;

    float sum = 0.f, ssq = 0.f;
    for (int f = ty; f < F; f += 16) {
        float v = src[f * WW + w0 + tx];
        sum += v; ssq += v * v;
    }
    __shared__ float sm[16][17], sq[16][17];
    __shared__ float mu_s[16], rs_s[16];
    sm[ty][tx] = sum; sq[ty][tx] = ssq;
    __syncthreads();
    if (threadIdx.x < 16) {
        float s = 0.f, q = 0.f;
        #pragma unroll
        for (int i = 0; i < 16; i++) { s += sm[i][threadIdx.x]; q += sq[i][threadIdx.x]; }
        float mu  = s * (1.f / F);
        float var = q * (1.f / F) - mu * mu;     // biased var (jnp.var)
        mu_s[threadIdx.x] = mu;
        rs_s[threadIdx.x] = rsqrtf(var + 1e-8f);
    }
    __syncthreads();
    float mu = mu_s[tx], rs = rs_s[tx];
    unsigned short* o = out + (size_t)c * F * WW;
    for (int f = ty; f < F; f += 16) {
        float v = src[f * WW + w0 + tx];
        float r = (v - mu) * rs * g[c * F + f] + b[c * F + f];
        o[f * WW + w0 + tx] = f2bf(r);
    }
}

// ---------------------------------------------------------------------------
// LN3 stats: mu/rsigma per (c,w) over F, 24 channels from x,z1,z2.
// ---------------------------------------------------------------------------
__global__ __launch_bounds__(256) void k_ln3_stats(
    const float* __restrict__ s0, const float* __restrict__ s1,
    const float* __restrict__ s2,
    float* __restrict__ mu3, float* __restrict__ rs3)
{
    int c  = blockIdx.x >> 5;
    int w0 = (blockIdx.x & 31) << 4;
    const float* src = (c < 8) ? s0 : (c < 16) ? s1 : s2;
    src += (size_t)(c & 7) * F * WW;
    int tx = threadIdx.x & 15, ty = threadIdx.x >> 4;

    float sum = 0.f, ssq = 0.f;
    for (int f = ty; f < F; f += 16) {
        float v = src[f * WW + w0 + tx];
        sum += v; ssq += v * v;
    }
    __shared__ float sm[16][17], sq[16][17];
    sm[ty][tx] = sum; sq[ty][tx] = ssq;
    __syncthreads();
    if (threadIdx.x < 16) {
        float s = 0.f, q = 0.f;
        #pragma unroll
        for (int i = 0; i < 16; i++) { s += sm[i][threadIdx.x]; q += sq[i][threadIdx.x]; }
        float mu  = s * (1.f / F);
        float var = q * (1.f / F) - mu * mu;
        mu3[c * WW + w0 + threadIdx.x] = mu;
        rs3[c * WW + w0 + threadIdx.x] = rsqrtf(var + 1e-8f);
    }
}

// ---------------------------------------------------------------------------
// LN3 apply: write nh3p channel-last padded [PF][PW][32] bf16; interior only.
// ---------------------------------------------------------------------------
__global__ __launch_bounds__(256) void k_ln3_apply(
    const float* __restrict__ s0, const float* __restrict__ s1,
    const float* __restrict__ s2,
    const float* __restrict__ mu3, const float* __restrict__ rs3,
    const float* __restrict__ g, const float* __restrict__ b,
    unsigned short* __restrict__ outp)
{
    int p = blockIdx.x * 256 + threadIdx.x;
    int f = p >> 9, w = p & 511;
    unsigned short buf[32];
    #pragma unroll
    for (int c = 0; c < 24; c++) {
        const float* src = (c < 8) ? s0 : (c < 16) ? s1 : s2;
        float v = src[((size_t)(c & 7) * F + f) * WW + w];
        float r = (v - mu3[c * WW + w]) * rs3[c * WW + w] * g[c * F + f] + b[c * F + f];
        buf[c] = f2bf(r);
    }
    #pragma unroll
    for (int c = 24; c < 32; c++) buf[c] = 0;
    unsigned short* op = outp + ((size_t)(f + 1) * PW + (w + 1)) * 32;
    #pragma unroll
    for (int q = 0; q < 4; q++) *(short8*)(op + q * 8) = *(const short8*)(buf + q * 8);
}

// ---------------------------------------------------------------------------
// Zero the spatial pad cells of the two padded channel-last buffers.
// ---------------------------------------------------------------------------
__global__ void k_pad(unsigned short* __restrict__ a, unsigned short* __restrict__ b)
{
    int i = blockIdx.x * 256 + threadIdx.x;
    if (i >= 3076) return;
    int f, w;
    if (i < 514)       { f = 0;    w = i; }
    else if (i < 1028) { f = 1025; w = i - 514; }
    else { int j = i - 1028; f = 1 + (j >> 1); w = (j & 1) ? 513 : 0; }
    size_t off = ((size_t)f * PW + w) * 32;
    short8 z = {};
    #pragma unroll
    for (int q = 0; q < 4; q++) {
        *(short8*)(a + off + q * 8) = z;
        *(short8*)(b + off + q * 8) = z;
    }
}

// ---------------------------------------------------------------------------
// Weight prep: pack conv weights as bf16 MFMA A-fragments.
// ---------------------------------------------------------------------------
__global__ void k_prep(const float* __restrict__ wc1, const float* __restrict__ wc2,
                       unsigned short* __restrict__ A1, unsigned short* __restrict__ A2)
{
    int i = blockIdx.x * 256 + threadIdx.x;
    if (i < 9216) {
        int ic = i & 31, row = i >> 5;       // row 0..287
        int o16 = row & 15, tm = row >> 4;   // tm 0..17
        int tap = tm >> 1, m = tm & 1;
        int oc = m * 16 + o16;
        A1[i] = (ic < 24) ? f2bf(wc1[(oc * 24 + ic) * 9 + tap]) : (unsigned short)0;
    }
    if (i < 4608) {
        int ic = i & 31, row = i >> 5;       // 0..143
        int o = row & 15, tap = row >> 4;
        A2[i] = (o < 8) ? f2bf(wc2[(o * 32 + ic) * 9 + tap]) : (unsigned short)0;
    }
}

// ---------------------------------------------------------------------------
// conv1 via implicit-GEMM MFMA: 24(->32)ch -> 32ch, 3x3, + SquaredReLU.
// ---------------------------------------------------------------------------
__global__ __launch_bounds__(256) void k_conv1m(
    const unsigned short* __restrict__ inp, const unsigned short* __restrict__ A1,
    unsigned short* __restrict__ outp)
{
    int wv = threadIdx.x >> 6, lane = threadIdx.x & 63;
    int lr = lane & 15, lkg = lane >> 4;

    short8 a[9][2];
    #pragma unroll
    for (int tap = 0; tap < 9; tap++)
        #pragma unroll
        for (int m = 0; m < 2; m++)
            a[tap][m] = *(const short8*)(A1 + ((tap * 2 + m) * 16 + lr) * 32 + lkg * 8);

    int f = blockIdx.x >> 1;
    int half = blockIdx.x & 1;
    for (int it = 0; it < 4; it++) {
        int w0 = (half * 16 + wv * 4 + it) * 16;
        float4v acc0 = {}, acc1 = {};
        #pragma unroll
        for (int dy = 0; dy < 3; dy++)
            #pragma unroll
            for (int dx = 0; dx < 3; dx++) {
                short8 bfrag = *(const short8*)(inp +
                    ((size_t)(f + dy) * PW + (w0 + lr + dx)) * 32 + lkg * 8);
                acc0 = __builtin_amdgcn_mfma_f32_16x16x32_bf16(a[dy*3+dx][0], bfrag, acc0, 0, 0, 0);
                acc1 = __builtin_amdgcn_mfma_f32_16x16x32_bf16(a[dy*3+dx][1], bfrag, acc1, 0, 0, 0);
            }
        unsigned short* op = outp + ((size_t)(f + 1) * PW + (w0 + lr + 1)) * 32;
        short4v o0, o1;
        #pragma unroll
        for (int r = 0; r < 4; r++) {
            float v0 = fmaxf(acc0[r], 0.f);
            float v1 = fmaxf(acc1[r], 0.f);
            o0[r] = (short)f2bf(v0 * v0);
            o1[r] = (short)f2bf(v1 * v1);
        }
        *(short4v*)(op + lkg * 4)      = o0;   // oc 0..15
        *(short4v*)(op + 16 + lkg * 4) = o1;   // oc 16..31
    }
}

// ---------------------------------------------------------------------------
// conv2 via implicit-GEMM MFMA: 32ch -> 8ch (pad 16), 3x3, + residual x.
// ---------------------------------------------------------------------------
__global__ __launch_bounds__(256) void k_conv2m(
    const unsigned short* __restrict__ inp, const unsigned short* __restrict__ A2,
    const float* __restrict__ x, float* __restrict__ out)
{
    int wv = threadIdx.x >> 6, lane = threadIdx.x & 63;
    int lr = lane & 15, lkg = lane >> 4;

    short8 a[9];
    #pragma unroll
    for (int tap = 0; tap < 9; tap++)
        a[tap] = *(const short8*)(A2 + (tap * 16 + lr) * 32 + lkg * 8);

    int f = blockIdx.x >> 1;
    int half = blockIdx.x & 1;
    for (int it = 0; it < 4; it++) {
        int w0 = (half * 16 + wv * 4 + it) * 16;
        float4v acc = {};
        #pragma unroll
        for (int dy = 0; dy < 3; dy++)
            #pragma unroll
            for (int dx = 0; dx < 3; dx++) {
                short8 bfrag = *(const short8*)(inp +
                    ((size_t)(f + dy) * PW + (w0 + lr + dx)) * 32 + lkg * 8);
                acc = __builtin_amdgcn_mfma_f32_16x16x32_bf16(a[dy*3+dx], bfrag, acc, 0, 0, 0);
            }
        if (lkg < 2) {
            #pragma unroll
            for (int r = 0; r < 4; r++) {
                int oc = lkg * 4 + r;
                size_t off = ((size_t)oc * F + f) * WW + w0 + lr;
                out[off] = x[off] + acc[r];
            }
        }
    }
}

// ---------------------------------------------------------------------------
// 1x3 conv along W producing q,k,v (8 out-ch each). q,k written DIRECTLY in
// transposed layout [pair][w][jf] via in-block LDS transpose: block owns a
// 32f x 32w tile (all 8 oc), so every 64B line of qT/kT (= 32 consecutive jf
// at one w) is assembled fully inside one block. v natural [oc][f][w].
// Thread map: tid = fy*8 + wx, 4 w-points/thread. grid = 32*16 = 512.
// ---------------------------------------------------------------------------
__global__ __launch_bounds__(256) void k_qkv(
    const unsigned short* __restrict__ srcQ, int CinQ, const float* __restrict__ wq,
    const void* __restrict__ srcKV, int kvBf16,
    const float* __restrict__ wk, const float* __restrict__ wv,
    unsigned short* __restrict__ qT, unsigned short* __restrict__ kT,
    unsigned short* __restrict__ v)
{
    int bf = blockIdx.x >> 4, bw = blockIdx.x & 15;
    int f0 = bf << 5, w0t = bw << 5;
    int fy = threadIdx.x >> 3, wx = threadIdx.x & 7;
    int f  = f0 + fy;
    int w0 = w0t + (wx << 2);
    int h  = f0 >> 7, jf0 = f0 & 127;

    __shared__ unsigned short T[8][32][33];   // [oc][w][fy], odd pitch

    // ---- Q conv ----
    float accq[8][4];
    #pragma unroll
    for (int o = 0; o < 8; o++) { accq[o][0]=0.f; accq[o][1]=0.f; accq[o][2]=0.f; accq[o][3]=0.f; }
    for (int ic = 0; ic < CinQ; ic++) {
        const unsigned short* s = srcQ + ((size_t)ic * F + f) * WW;
        float val[6];
        #pragma unroll
        for (int i = 0; i < 6; i++) {
            int w = w0 - 1 + i;
            val[i] = (w >= 0 && w < WW) ? bf2f(s[w]) : 0.f;
        }
        #pragma unroll
        for (int o = 0; o < 8; o++)
            #pragma unroll
            for (int t = 0; t < 3; t++) {
                float wt = wq[(o * CinQ + ic) * 3 + t];
                #pragma unroll
                for (int p = 0; p < 4; p++) accq[o][p] = fmaf(wt, val[p + t], accq[o][p]);
            }
    }
    #pragma unroll
    for (int o = 0; o < 8; o++)
        #pragma unroll
        for (int p = 0; p < 4; p++)
            T[o][(wx << 2) + p][fy] = f2bf(accq[o][p]);

    // ---- K and V conv (8 in-ch always) ----
    float acck[8][4], accv[8][4];
    #pragma unroll
    for (int o = 0; o < 8; o++)
        #pragma unroll
        for (int p = 0; p < 4; p++) { acck[o][p] = 0.f; accv[o][p] = 0.f; }
    for (int ic = 0; ic < 8; ic++) {
        float val[6];
        if (kvBf16) {
            const unsigned short* s = (const unsigned short*)srcKV + ((size_t)ic * F + f) * WW;
            #pragma unroll
            for (int i = 0; i < 6; i++) {
                int w = w0 - 1 + i;
                val[i] = (w >= 0 && w < WW) ? bf2f(s[w]) : 0.f;
            }
        } else {
            const float* s = (const float*)srcKV + ((size_t)ic * F + f) * WW;
            #pragma unroll
            for (int i = 0; i < 6; i++) {
                int w = w0 - 1 + i;
                val[i] = (w >= 0 && w < WW) ? s[w] : 0.f;
            }
        }
        #pragma unroll
        for (int o = 0; o < 8; o++)
            #pragma unroll
            for (int t = 0; t < 3; t++) {
                float wtk = wk[(o * 8 + ic) * 3 + t];
                float wtv = wv[(o * 8 + ic) * 3 + t];
                #pragma unroll
                for (int p = 0; p < 4; p++) {
                    acck[o][p] = fmaf(wtk, val[p + t], acck[o][p]);
                    accv[o][p] = fmaf(wtv, val[p + t], accv[o][p]);
                }
            }
    }
    // v natural store (8 consecutive lanes cover one 64B line)
    #pragma unroll
    for (int o = 0; o < 8; o++) {
        short4v tv;
        #pragma unroll
        for (int p = 0; p < 4; p++) tv[p] = (short)f2bf(accv[o][p]);
        *(short4v*)(v + ((size_t)o * F + f) * WW + w0) = tv;
    }

    __syncthreads();
    // q transposed write: 1024 short8 units; consecutive tid -> consecutive jq
    // -> 4 lanes assemble one FULL 64B line.
    #pragma unroll
    for (int it = 0; it < 4; it++) {
        int u = it * 256 + threadIdx.x;
        int jq = u & 3, w = (u >> 2) & 31, o = u >> 7;
        short8 vv;
        #pragma unroll
        for (int i = 0; i < 8; i++) vv[i] = (short)T[o][w][jq * 8 + i];
        *(short8*)(qT + ((size_t)((o << 3) + h) * WW + w0t + w) * DH + jf0 + (jq << 3)) = vv;
    }
    __syncthreads();
    #pragma unroll
    for (int o = 0; o < 8; o++)
        #pragma unroll
        for (int p = 0; p < 4; p++)
            T[o][(wx << 2) + p][fy] = f2bf(acck[o][p]);
    __syncthreads();
    #pragma unroll
    for (int it = 0; it < 4; it++) {
        int u = it * 256 + threadIdx.x;
        int jq = u & 3, w = (u >> 2) & 31, o = u >> 7;
        short8 vv;
        #pragma unroll
        for (int i = 0; i < 8; i++) vv[i] = (short)T[o][w][jq * 8 + i];
        *(short8*)(kT + ((size_t)((o << 3) + h) * WW + w0t + w) * DH + jf0 + (jq << 3)) = vv;
    }
}

// ---------------------------------------------------------------------------
// Fused flash attention. This round: T14 issue-early/write-late K/V staging
// (prefetch chunk kc+1 into 32 VGPRs at chunk top; ds_write after the
// read-barrier -> global latency hides under the whole chunk's compute),
// setprio(1) around MFMA clusters, launch_bounds(256,2) caps VGPR at 256.
// Block: 256 thr (4 waves x 16 q rows). grid = 512, pair-major for XCD/L2.
// ---------------------------------------------------------------------------
__global__ __launch_bounds__(256, 2) void k_attn(
    const unsigned short* __restrict__ qT, const unsigned short* __restrict__ kT,
    const unsigned short* __restrict__ v,
    const float* __restrict__ a0, const float* __restrict__ a1,
    const float* __restrict__ a2, int nsrc,
    float* __restrict__ pq, unsigned short* __restrict__ aout)
{
    int pair = blockIdx.x & 63;          // phys mod 8 == pair mod 8 -> same XCD
    int qw0  = (blockIdx.x >> 6) << 6;

    __shared__ unsigned short Ks[64 * 136];   // [k][d], pad 8 -> row 272B
    __shared__ unsigned short Vt[128 * 72];   // [d][k-chunk], pad 8 -> row 144B
    __shared__ unsigned short P [64 * 72];    // [q][k-chunk], wave-private rows

    int tid = threadIdx.x;
    const unsigned short* qb = qT + ((size_t)pair * WW + qw0) * DH;
    const unsigned short* kb = kT + (size_t)pair * WW * DH;
    const unsigned short* vb = v  + (size_t)pair * DH * WW;

    int wv = tid >> 6, lane = tid & 63;
    int lr = lane & 15, lkg = lane >> 4;
    int qrow = qw0 + wv * 16 + lr;

    short8 bq[4];
    #pragma unroll
    for (int dk = 0; dk < 4; dk++)
        bq[dk] = *(const short8*)(qb + (size_t)(wv * 16 + lr) * DH + dk * 32 + lkg * 8);

    // stage chunk 0 directly
    #pragma unroll
    for (int it = 0; it < 4; it++) {
        int idx = it * 256 + tid;
        int r = idx >> 4, c = idx & 15;
        *(short8*)(Ks + r * 136 + c * 8) = *(const short8*)(kb + (size_t)r * DH + c * 8);
    }
    #pragma unroll
    for (int it = 0; it < 4; it++) {
        int idx = it * 256 + tid;
        int j = idx >> 3, c = idx & 7;
        *(short8*)(Vt + j * 72 + c * 8) = *(const short8*)(vb + (size_t)j * WW + c * 8);
    }
    __syncthreads();

    float4v acc[8] = {};
    float mrun = -1e30f, lrun = 0.f;
    const float scale = 0.08838834764831845f;   // 1/sqrt(128)
    size_t bbase = (size_t)pair * WW * WW + (size_t)qrow * WW;

    for (int kc = 0; kc < 8; kc++) {
        // ---- prefetch next chunk's K/V into registers (issue-early) ----
        short8 krx[4], vrx[4];
        if (kc < 7) {
            #pragma unroll
            for (int it = 0; it < 4; it++) {
                int idx = it * 256 + tid;
                int r = idx >> 4, c = idx & 15;
                krx[it] = *(const short8*)(kb + (size_t)((kc + 1) * 64 + r) * DH + c * 8);
            }
            #pragma unroll
            for (int it = 0; it < 4; it++) {
                int idx = it * 256 + tid;
                int j = idx >> 3, c = idx & 7;
                vrx[it] = *(const short8*)(vb + (size_t)j * WW + (kc + 1) * 64 + c * 8);
            }
        }
        // ---- bias loads (consumed after QK) ----
        float4v b0v[4], b1v[4], b2v[4];
        #pragma unroll
        for (int mi = 0; mi < 4; mi++)
            b0v[mi] = *(const float4v*)(a0 + bbase + kc * 64 + mi * 16 + lkg * 4);
        if (nsrc > 1) {
            #pragma unroll
            for (int mi = 0; mi < 4; mi++)
                b1v[mi] = *(const float4v*)(a1 + bbase + kc * 64 + mi * 16 + lkg * 4);
        }
        if (nsrc > 2) {
            #pragma unroll
            for (int mi = 0; mi < 4; mi++)
                b2v[mi] = *(const float4v*)(a2 + bbase + kc * 64 + mi * 16 + lkg * 4);
        }

        // S^T: D[k 64][q 16-per-wave], contraction over d=128
        float4v sacc[4] = {};
        __builtin_amdgcn_s_setprio(1);
        #pragma unroll
        for (int dk = 0; dk < 4; dk++) {
            short8 ak[4];
            #pragma unroll
            for (int mi = 0; mi < 4; mi++)
                ak[mi] = *(const short8*)(Ks + (mi * 16 + lr) * 136 + dk * 32 + lkg * 8);
            #pragma unroll
            for (int mi = 0; mi < 4; mi++)
                sacc[mi] = __builtin_amdgcn_mfma_f32_16x16x32_bf16(ak[mi], bq[dk], sacc[mi], 0, 0, 0);
        }
        __builtin_amdgcn_s_setprio(0);

        float sv[4][4];
        float mx = -1e30f;
        #pragma unroll
        for (int mi = 0; mi < 4; mi++) {
            int k0 = kc * 64 + mi * 16 + lkg * 4;
            float4v s;
            #pragma unroll
            for (int r = 0; r < 4; r++) s[r] = sacc[mi][r] * scale + b0v[mi][r];
            if (nsrc > 1) {
                #pragma unroll
                for (int r = 0; r < 4; r++) s[r] += b1v[mi][r];
            }
            if (nsrc > 2) {
                #pragma unroll
                for (int r = 0; r < 4; r++) s[r] += b2v[mi][r];
            }
            *(float4v*)(pq + bbase + k0) = s;
            #pragma unroll
            for (int r = 0; r < 4; r++) { sv[mi][r] = s[r]; mx = fmaxf(mx, s[r]); }
        }
        mx = fmaxf(mx, __shfl_xor(mx, 16));
        mx = fmaxf(mx, __shfl_xor(mx, 32));
        float mnew  = fmaxf(mrun, mx);
        float alpha = __expf(mrun - mnew);
        float lsum  = 0.f;
        #pragma unroll
        for (int mi = 0; mi < 4; mi++) {
            short4v pk;
            #pragma unroll
            for (int r = 0; r < 4; r++) {
                float e = __expf(sv[mi][r] - mnew);
                lsum += e;
                pk[r] = (short)f2bf(e);
            }
            *(short4v*)(P + (wv * 16 + lr) * 72 + mi * 16 + lkg * 4) = pk;
        }
        lsum += __shfl_xor(lsum, 16);
        lsum += __shfl_xor(lsum, 32);
        lrun = lrun * alpha + lsum;
        mrun = mnew;

        #pragma unroll
        for (int mt = 0; mt < 8; mt++)
            #pragma unroll
            for (int r = 0; r < 4; r++) acc[mt][r] *= alpha;

        // PV: D[d 128][q 16], contraction over this 64-k chunk
        __builtin_amdgcn_s_setprio(1);
        #pragma unroll
        for (int ks = 0; ks < 2; ks++) {
            short8 bp = *(const short8*)(P + (wv * 16 + lr) * 72 + ks * 32 + lkg * 8);
            #pragma unroll
            for (int mt = 0; mt < 8; mt++) {
                short8 av = *(const short8*)(Vt + (mt * 16 + lr) * 72 + ks * 32 + lkg * 8);
                acc[mt] = __builtin_amdgcn_mfma_f32_16x16x32_bf16(av, bp, acc[mt], 0, 0, 0);
            }
        }
        __builtin_amdgcn_s_setprio(0);

        __syncthreads();   // all waves done reading Ks/Vt
        if (kc < 7) {
            #pragma unroll
            for (int it = 0; it < 4; it++) {
                int idx = it * 256 + tid;
                int r = idx >> 4, c = idx & 15;
                *(short8*)(Ks + r * 136 + c * 8) = krx[it];
            }
            #pragma unroll
            for (int it = 0; it < 4; it++) {
                int idx = it * 256 + tid;
                int j = idx >> 3, c = idx & 7;
                *(short8*)(Vt + j * 72 + c * 8) = vrx[it];
            }
        }
        __syncthreads();   // staging complete
    }

    float linv = 1.f / lrun;
    unsigned short* ab = aout + (size_t)pair * DH * WW + qw0 + wv * 16 + lr;
    #pragma unroll
    for (int mt = 0; mt < 8; mt++)
        #pragma unroll
        for (int r = 0; r < 4; r++) {
            int d = mt * 16 + lkg * 4 + r;
            ab[(size_t)d * WW] = f2bf(acc[mt][r] * linv);
        }
}

// ---------------------------------------------------------------------------
// wo conv: 1x3, 8->8, bf16 in (natural), fp32 out. 4 points/thread.
// ---------------------------------------------------------------------------
__global__ __launch_bounds__(256) void k_wo(
    const unsigned short* __restrict__ a, const float* __restrict__ w,
    float* __restrict__ z)
{
    int p0 = (blockIdx.x * 256 + threadIdx.x) * 4;
    int f = p0 >> 9, w0 = p0 & 511;
    float acc[8][4];
    #pragma unroll
    for (int o = 0; o < 8; o++)
        #pragma unroll
        for (int p = 0; p < 4; p++) acc[o][p] = 0.f;
    for (int ic = 0; ic < 8; ic++) {
        const unsigned short* s = a + ((size_t)ic * F + f) * WW;
        float val[6];
        #pragma unroll
        for (int i = 0; i < 6; i++) {
            int ww = w0 - 1 + i;
            val[i] = (ww >= 0 && ww < WW) ? bf2f(s[ww]) : 0.f;
        }
        #pragma unroll
        for (int o = 0; o < 8; o++)
            #pragma unroll
            for (int t = 0; t < 3; t++) {
                float wt = w[(o * 8 + ic) * 3 + t];
                #pragma unroll
                for (int p = 0; p < 4; p++) acc[o][p] = fmaf(wt, val[p + t], acc[o][p]);
            }
    }
    #pragma unroll
    for (int o = 0; o < 8; o++) {
        float4v ov;
        #pragma unroll
        for (int p = 0; p < 4; p++) ov[p] = acc[o][p];
        *(float4v*)(z + ((size_t)o * F + f) * WW + w0) = ov;
    }
}

// ---------------------------------------------------------------------------
extern "C" void kernel_launch(void* const* d_in, const int* in_sizes, int n_in,
                              void* d_out, int out_size, void* d_ws, size_t ws_size,
                              hipStream_t stream) {
    const float* x        = (const float*)d_in[0];
    const float* skip     = (const float*)d_in[1];
    const float* prev_qk1 = (const float*)d_in[2];
    const float* prev_qk2 = (const float*)d_in[3];
    const float* skip_qk  = (const float*)d_in[4];
    const float* g1  = (const float*)d_in[5];
    const float* b1  = (const float*)d_in[6];
    const float* wq1 = (const float*)d_in[7];
    const float* wk1 = (const float*)d_in[8];
    const float* wv1 = (const float*)d_in[9];
    const float* wo1 = (const float*)d_in[10];
    const float* g2  = (const float*)d_in[11];
    const float* b2  = (const float*)d_in[12];
    const float* wq2 = (const float*)d_in[13];
    const float* wk2 = (const float*)d_in[14];
    const float* wv2 = (const float*)d_in[15];
    const float* wo2 = (const float*)d_in[16];
    const float* g3  = (const float*)d_in[17];
    const float* b3  = (const float*)d_in[18];
    const float* wc1 = (const float*)d_in[19];
    const float* wc2 = (const float*)d_in[20];

    char* ws = (char*)d_ws;
    // Phase-overlapped workspace (peak ~101.2 MB):
    float*          z1 = (float*)(ws + 0);                   // 16.78MB
    float*          z2 = (float*)(ws + 16777216);            // 16.78MB
    // Region R: attn phase layout
    unsigned short* qT = (unsigned short*)(ws + 33554432);   //  8.39MB [pair][w][jf]
    unsigned short* kT = (unsigned short*)(ws + 41943040);   //  8.39MB
    unsigned short* vB = (unsigned short*)(ws + 50331648);   //  8.39MB natural
    unsigned short* nh = (unsigned short*)(ws + 58720256);   // 16.78MB (ln1/ln2 out)
    unsigned short* aB = (unsigned short*)(ws + 75497472);   //  8.39MB
    // Region R: MLP phase layout (aliases the above; attn bufs dead by then)
    unsigned short* nh3p = (unsigned short*)(ws + 33554432); // 33.75MB [PF][PW][32] bf16
    unsigned short* tBp  = (unsigned short*)(ws + 67305728); // 33.75MB
    unsigned short* A1p  = (unsigned short*)(ws + 101057024);// 18KB
    unsigned short* A2p  = (unsigned short*)(ws + 101075456);//  9KB
    float*          mu3  = (float*)(ws + 101084672);         // 48KB
    float*          rs3  = (float*)(ws + 101133824);         // 48KB

    float* out0 = (float*)d_out;
    float* pq1  = out0 + 4194304;
    float* pq2  = pq1 + 16777216;

    k_prep<<<36, 256, 0, stream>>>(wc1, wc2, A1p, A2p);

    // --- attn1: x -> ln1 -> qkv (direct transposed q,k) -> fused attn -> wo
    k_ln  <<<8 * 32,  256, 0, stream>>>(x, nullptr, nullptr, g1, b1, nh);
    k_qkv <<<512,     256, 0, stream>>>(nh, 8, wq1, nh, 1, wk1, wv1, qT, kT, vB);
    k_attn<<<512,     256, 0, stream>>>(qT, kT, vB, prev_qk1, skip_qk, nullptr, 2, pq1, aB);
    k_wo  <<<512,     256, 0, stream>>>(aB, wo1, z1);

    // --- attn2: [x,z1] -> ln2 -> q ; k,v from raw skip
    k_ln  <<<16 * 32, 256, 0, stream>>>(x, z1, nullptr, g2, b2, nh);
    k_qkv <<<512,     256, 0, stream>>>(nh, 16, wq2, skip, 0, wk2, wv2, qT, kT, vB);
    k_attn<<<512,     256, 0, stream>>>(qT, kT, vB, skip_qk, pq1, prev_qk2, 3, pq2, aB);
    k_wo  <<<512,     256, 0, stream>>>(aB, wo2, z2);

    // --- MLP: ln3([x,z1,z2]) channel-last -> MFMA conv3x3(24->32) -> sqrelu
    //          -> MFMA conv3x3(32->8) + x.
    k_pad      <<<13,      256, 0, stream>>>(nh3p, tBp);
    k_ln3_stats<<<24 * 32, 256, 0, stream>>>(x, z1, z2, mu3, rs3);
    k_ln3_apply<<<2048,    256, 0, stream>>>(x, z1, z2, mu3, rs3, g3, b3, nh3p);
    k_conv1m   <<<2048,    256, 0, stream>>>(nh3p, A1p, tBp);
    k_conv2m   <<<2048,    256, 0, stream>>>(tBp, A2p, x, out0);
}